// Round 6
// baseline (545.369 us; speedup 1.0000x reference)
//
#include <hip/hip_runtime.h>
#include <math.h>

#define N_NODES 50000
#define N_EDGES 400000
#define H_HEADS 8
#define D_HEAD 16
#define R_TYPES 6
#define T_TYPES 4
#define DIM 128
#define BN 16                                      // nodes per GEMM tile
#define MAX_TILES ((N_NODES + BN - 1) / BN + T_TYPES)
#define NBLK_E ((N_EDGES + 255) / 256)             // 1563
#define AGG_W 64                                   // aggregation window (edges)

// ======================= CSR build (group edges by dst) =======================

__global__ void k_count(const int* __restrict__ dst, int* __restrict__ deg, int n) {
    int e = blockIdx.x * blockDim.x + threadIdx.x;
    if (e < n) atomicAdd(&deg[dst[e]], 1);
}

__global__ void k_scanA(const int* __restrict__ deg, int* __restrict__ offs,
                        int* __restrict__ partial, int n) {
    __shared__ int tmp[256];
    int tid = threadIdx.x;
    int i = blockIdx.x * 256 + tid;
    int v = (i < n) ? deg[i] : 0;
    tmp[tid] = v;
    __syncthreads();
    for (int o = 1; o < 256; o <<= 1) {
        int t = (tid >= o) ? tmp[tid - o] : 0;
        __syncthreads();
        tmp[tid] += t;
        __syncthreads();
    }
    if (i < n) offs[i] = tmp[tid] - v;
    if (tid == 255) partial[blockIdx.x] = tmp[255];
}

__global__ void k_scanB(int* __restrict__ partial, int nb) {
    __shared__ int tmp[256];
    int tid = threadIdx.x;
    int v = (tid < nb) ? partial[tid] : 0;
    tmp[tid] = v;
    __syncthreads();
    for (int o = 1; o < 256; o <<= 1) {
        int t = (tid >= o) ? tmp[tid - o] : 0;
        __syncthreads();
        tmp[tid] += t;
        __syncthreads();
    }
    if (tid < nb) partial[tid] = tmp[tid] - v;
}

__global__ void k_scanC(int* __restrict__ offs, const int* __restrict__ partial, int n) {
    int i = blockIdx.x * 256 + threadIdx.x;
    if (i < n) offs[i] += partial[blockIdx.x];
}

// scatter edges into CSR order, materializing src/dst/etype at sorted position
__global__ void k_scatter2(const int* __restrict__ src, const int* __restrict__ dst,
                           const int* __restrict__ etype, int* __restrict__ offs,
                           int* __restrict__ esrc_s, int* __restrict__ edst_s,
                           int* __restrict__ ety_s, int n) {
    int e = blockIdx.x * blockDim.x + threadIdx.x;
    if (e < n) {
        int pos = atomicAdd(&offs[dst[e]], 1);   // offs becomes END offset
        esrc_s[pos] = src[e];
        edst_s[pos] = dst[e];
        ety_s[pos]  = etype[e];
    }
}

// ======================= r-sort of CSR positions (counting sort) ==============

__global__ void k_rhist(const int* __restrict__ ety_s, int* __restrict__ rcnt, int n) {
    __shared__ int h[R_TYPES];
    int tid = threadIdx.x;
    if (tid < R_TYPES) h[tid] = 0;
    __syncthreads();
    int i = blockIdx.x * 256 + tid;
    if (i < n) atomicAdd(&h[ety_s[i]], 1);
    __syncthreads();
    if (tid < R_TYPES) rcnt[tid * NBLK_E + blockIdx.x] = h[tid];
}

__global__ void k_rscan(int* __restrict__ a, int total) {
    __shared__ int tmp[256];
    __shared__ int carry_s;
    int tid = threadIdx.x;
    if (tid == 0) carry_s = 0;
    __syncthreads();
    for (int base = 0; base < total; base += 256) {
        int i = base + tid;
        int v = (i < total) ? a[i] : 0;
        tmp[tid] = v;
        __syncthreads();
        for (int o = 1; o < 256; o <<= 1) {
            int t = (tid >= o) ? tmp[tid - o] : 0;
            __syncthreads();
            tmp[tid] += t;
            __syncthreads();
        }
        int carry = carry_s;
        if (i < total) a[i] = carry + tmp[tid] - v;   // exclusive
        __syncthreads();
        if (tid == 255) carry_s = carry + tmp[255];
        __syncthreads();
    }
}

__global__ void k_rscatter(const int* __restrict__ esrc_s, const int* __restrict__ edst_s,
                           const int* __restrict__ ety_s, const int* __restrict__ rbase,
                           int* __restrict__ sp_src, int* __restrict__ sp_dst,
                           int* __restrict__ sp_r, int* __restrict__ sp_pos, int n) {
    __shared__ int hist[R_TYPES];
    __shared__ int base[R_TYPES];
    int tid = threadIdx.x;
    if (tid < R_TYPES) hist[tid] = 0;
    __syncthreads();
    int p = blockIdx.x * 256 + tid;
    int r = 0, rank = 0;
    if (p < n) {
        r = ety_s[p];
        rank = atomicAdd(&hist[r], 1);
    }
    __syncthreads();
    if (tid < R_TYPES) base[tid] = rbase[tid * NBLK_E + blockIdx.x];
    __syncthreads();
    if (p < n) {
        int q2 = base[r] + rank;
        sp_src[q2] = esrc_s[p];
        sp_dst[q2] = edst_s[p];
        sp_r[q2]   = r;
        sp_pos[q2] = p;
    }
}

// ======================= node type bucketing (padded 16-node tiles) ===========

__global__ void k_tcount_agg(const int* __restrict__ ntype, int* __restrict__ tcnt,
                             int* __restrict__ wpos, int n) {
    __shared__ int hist[T_TYPES];
    __shared__ int base[T_TYPES];
    int tid = threadIdx.x;
    if (tid < T_TYPES) hist[tid] = 0;
    __syncthreads();
    int i = blockIdx.x * 256 + tid;
    int t = 0, rank = 0;
    if (i < n) {
        t = ntype[i];
        rank = atomicAdd(&hist[t], 1);
    }
    __syncthreads();
    if (tid < T_TYPES)
        base[tid] = (hist[tid] > 0) ? atomicAdd(&tcnt[tid], hist[tid]) : 0;
    __syncthreads();
    if (i < n) wpos[i] = base[t] + rank;
}

__global__ void k_tsetup(const int* __restrict__ tcnt, int* __restrict__ pbase,
                         int* __restrict__ ntiles_g, int* __restrict__ tile_type) {
    __shared__ int off[T_TYPES + 1];
    if (threadIdx.x == 0) {
        int o = 0;
        for (int t = 0; t < T_TYPES; ++t) {
            off[t] = o;
            pbase[t] = o * BN;
            o += (tcnt[t] + BN - 1) / BN;
        }
        off[T_TYPES] = o;
        *ntiles_g = o;
    }
    __syncthreads();
    int total = off[T_TYPES];
    for (int i = threadIdx.x; i < total; i += blockDim.x) {
        int t = 0;
        while (t < T_TYPES - 1 && i >= off[t + 1]) ++t;
        tile_type[i] = t;
    }
}

__global__ void k_tscatter2(const int* __restrict__ ntype, const int* __restrict__ wpos,
                            const int* __restrict__ pbase, int* __restrict__ nlist, int n) {
    int i = blockIdx.x * 256 + threadIdx.x;
    if (i < n) nlist[pbase[ntype[i]] + wpos[i]] = i;
}

// ======================= K1: tiled typed-linear k,q,v (v2) =======================
// block = 4 tiles x (3 mats x 32 threads). Each thread: 4 cols x 16 nodes.
// Per d-quad: 4 float4 weight loads + 16 ds_read_b128 + 256 FMAs (FMA:LDS = 16:1).

__global__ __launch_bounds__(384) void k_kqv_gemm2(
    const float* __restrict__ x, const int* __restrict__ nlist,
    const int* __restrict__ tile_type, const int* __restrict__ ntiles_g,
    const float* __restrict__ Wk, const float* __restrict__ Wq,
    const float* __restrict__ Wv,
    float* __restrict__ kb, float* __restrict__ qb, float* __restrict__ vb) {
    __shared__ float xs[4 * BN][DIM];   // 32 KB
    __shared__ int sids[4 * BN];
    int tid = threadIdx.x;
    int b = blockIdx.x;
    int nt = *ntiles_g;
    if (tid < 4 * BN) {
        int tb0 = b * 4 + (tid >> 4);
        sids[tid] = (tb0 < nt) ? nlist[tb0 * BN + (tid & 15)] : -1;
    }
    __syncthreads();
    // float4 staging: 64 rows x 32 quads = 2048 quads
    for (int idx = tid; idx < 4 * BN * (DIM / 4); idx += 384) {
        int row = idx >> 5;
        int q4 = idx & 31;
        int nid = sids[row];
        float4 v4 = make_float4(0.f, 0.f, 0.f, 0.f);
        if (nid >= 0) v4 = *(const float4*)(x + (size_t)nid * DIM + q4 * 4);
        *(float4*)(&xs[row][q4 * 4]) = v4;
    }
    __syncthreads();
    int lt = tid / 96;            // local tile 0..3
    int wi = tid % 96;
    int mat = wi >> 5;            // 0=k 1=q 2=v
    int colq = wi & 31;           // column quad (cols 4*colq..4*colq+3)
    int tb = b * 4 + lt;
    if (tb >= nt) return;
    int t = tile_type[tb];
    const float* W = (mat == 0 ? Wk : (mat == 1 ? Wq : Wv))
                     + (size_t)t * DIM * DIM + colq * 4;
    float acc[BN][4];
#pragma unroll
    for (int n = 0; n < BN; ++n) {
        acc[n][0] = 0.f; acc[n][1] = 0.f; acc[n][2] = 0.f; acc[n][3] = 0.f;
    }
    const float* xbase = &xs[lt * BN][0];
    for (int dq = 0; dq < 32; ++dq) {
        float4 w0 = *(const float4*)(W + (size_t)(dq * 4 + 0) * DIM);
        float4 w1 = *(const float4*)(W + (size_t)(dq * 4 + 1) * DIM);
        float4 w2 = *(const float4*)(W + (size_t)(dq * 4 + 2) * DIM);
        float4 w3 = *(const float4*)(W + (size_t)(dq * 4 + 3) * DIM);
#pragma unroll
        for (int n = 0; n < BN; ++n) {
            float4 xv = *(const float4*)(xbase + n * DIM + dq * 4);
            acc[n][0] = fmaf(xv.x, w0.x, acc[n][0]);
            acc[n][0] = fmaf(xv.y, w1.x, acc[n][0]);
            acc[n][0] = fmaf(xv.z, w2.x, acc[n][0]);
            acc[n][0] = fmaf(xv.w, w3.x, acc[n][0]);
            acc[n][1] = fmaf(xv.x, w0.y, acc[n][1]);
            acc[n][1] = fmaf(xv.y, w1.y, acc[n][1]);
            acc[n][1] = fmaf(xv.z, w2.y, acc[n][1]);
            acc[n][1] = fmaf(xv.w, w3.y, acc[n][1]);
            acc[n][2] = fmaf(xv.x, w0.z, acc[n][2]);
            acc[n][2] = fmaf(xv.y, w1.z, acc[n][2]);
            acc[n][2] = fmaf(xv.z, w2.z, acc[n][2]);
            acc[n][2] = fmaf(xv.w, w3.z, acc[n][2]);
            acc[n][3] = fmaf(xv.x, w0.w, acc[n][3]);
            acc[n][3] = fmaf(xv.y, w1.w, acc[n][3]);
            acc[n][3] = fmaf(xv.z, w2.w, acc[n][3]);
            acc[n][3] = fmaf(xv.w, w3.w, acc[n][3]);
        }
    }
    float* ob = (mat == 0 ? kb : (mat == 1 ? qb : vb));
#pragma unroll
    for (int n = 0; n < BN; ++n) {
        int nid = sids[lt * BN + n];
        if (nid >= 0)
            *(float4*)(ob + (size_t)nid * DIM + colq * 4) =
                make_float4(acc[n][0], acc[n][1], acc[n][2], acc[n][3]);
    }
}

// ======================= K2: per-edge attention logits (r-sorted) =============

__global__ __launch_bounds__(256) void k_edge_a2(
    const float* __restrict__ kbuf, const float* __restrict__ qbuf,
    const int* __restrict__ sp_src, const int* __restrict__ sp_dst,
    const int* __restrict__ sp_r, const int* __restrict__ sp_pos,
    const float* __restrict__ rel_att, const float* __restrict__ rel_pri,
    float* __restrict__ a_ws, int nE) {
    __shared__ float A2[2][8 * 260];   // 2 r-slots, 8 heads, 16x16 each (stride 260)
    __shared__ float pri[2][8];
    __shared__ int r01[2];
    int b = blockIdx.x;
    int e0 = b * 32;
    int tid = threadIdx.x;
    int nHere = nE - e0; if (nHere > 32) nHere = 32;
    if (nHere <= 0) return;
    if (tid == 0) { r01[0] = sp_r[e0]; r01[1] = sp_r[e0 + nHere - 1]; }
    __syncthreads();
    int r0 = r01[0], r1 = r01[1];
    for (int idx = tid; idx < 2 * 2048; idx += 256) {
        int slot = idx >> 11;
        if (slot == 1 && r1 == r0) break;      // slot1 unused when uniform
        int rem = idx & 2047;
        int h = rem >> 8, dj = rem & 255;
        int rr = slot ? r1 : r0;
        A2[slot][h * 260 + dj] = rel_att[(h * R_TYPES + rr) * 256 + dj];
    }
    if (tid < 16) {
        int slot = tid >> 3, h = tid & 7;
        pri[slot][h] = rel_pri[h * R_TYPES + (slot ? r1 : r0)] * 0.25f;
    }
    __syncthreads();
    int el = tid >> 3;      // entry 0..31
    int h  = tid & 7;
    int q2 = e0 + el;
    if (q2 >= nE) return;
    int s = sp_src[q2], dn = sp_dst[q2], r = sp_r[q2];
    int slot = (r == r0) ? 0 : 1;
    const float4* kp = (const float4*)(kbuf + (size_t)s  * DIM + h * 16);
    const float4* qp = (const float4*)(qbuf + (size_t)dn * DIM + h * 16);
    float4 k4[4], q4[4];
#pragma unroll
    for (int i = 0; i < 4; ++i) { k4[i] = kp[i]; q4[i] = qp[i]; }
    float kk[16] = {k4[0].x,k4[0].y,k4[0].z,k4[0].w, k4[1].x,k4[1].y,k4[1].z,k4[1].w,
                    k4[2].x,k4[2].y,k4[2].z,k4[2].w, k4[3].x,k4[3].y,k4[3].z,k4[3].w};
    float qq[16] = {q4[0].x,q4[0].y,q4[0].z,q4[0].w, q4[1].x,q4[1].y,q4[1].z,q4[1].w,
                    q4[2].x,q4[2].y,q4[2].z,q4[2].w, q4[3].x,q4[3].y,q4[3].z,q4[3].w};
    const float4* A4 = (const float4*)&A2[slot][h * 260];
    float accj[16];
#pragma unroll
    for (int j = 0; j < 16; ++j) accj[j] = 0.f;
#pragma unroll
    for (int d = 0; d < 16; ++d) {
        float kd = kk[d];
#pragma unroll
        for (int jj = 0; jj < 4; ++jj) {
            float4 a4 = A4[d * 4 + jj];
            accj[jj * 4 + 0] = fmaf(kd, a4.x, accj[jj * 4 + 0]);
            accj[jj * 4 + 1] = fmaf(kd, a4.y, accj[jj * 4 + 1]);
            accj[jj * 4 + 2] = fmaf(kd, a4.z, accj[jj * 4 + 2]);
            accj[jj * 4 + 3] = fmaf(kd, a4.w, accj[jj * 4 + 3]);
        }
    }
    float acc = 0.f;
#pragma unroll
    for (int j = 0; j < 16; ++j) acc = fmaf(accj[j], qq[j], acc);
    a_ws[(size_t)sp_pos[q2] * 8 + h] = acc * pri[slot][h];
}

// ======================= K3: per-node softmax + aggregation (v4) ==============
// Persistent 128-thread blocks, one node at a time (grid-stride). rel_msg held
// in 96 registers/thread (loaded once per block lifetime). a/src/ety staged
// coalesced into LDS per 64-edge window with online-softmax rescale.

__global__ __launch_bounds__(128, 4) void k_aggregate4(
    const float* __restrict__ vbuf, const float* __restrict__ a_ws,
    const int* __restrict__ offs_end, const int* __restrict__ deg,
    const int* __restrict__ esrc_s, const int* __restrict__ ety_s,
    const float* __restrict__ rel_msg,
    float* __restrict__ hacc, int n) {
    __shared__ float al[AGG_W][8];     // 2 KB  (a-values: [edge][head])
    __shared__ int   sl[AGG_W];
    __shared__ int   rl[AGG_W];
    __shared__ float bl[R_TYPES][128]; // 3 KB  (buckets for the mix epilogue)
    int tid = threadIdx.x;
    int h = tid >> 4, d = tid & 15;
    // rel_msg column for this (h,d): m_reg[r][dp] = M[h][r][dp][d]
    float m_reg[R_TYPES][16];
#pragma unroll
    for (int r = 0; r < R_TYPES; ++r)
#pragma unroll
        for (int dp = 0; dp < 16; ++dp)
            m_reg[r][dp] = rel_msg[(((size_t)h * R_TYPES + r) * 16 + dp) * 16 + d];

    for (int node = blockIdx.x; node < n; node += gridDim.x) {
        int end = offs_end[node];
        int dg  = deg[node];
        int start = end - dg;
        float mrun = -1e30f, den = 0.f;
        float accR[R_TYPES] = {0.f, 0.f, 0.f, 0.f, 0.f, 0.f};
        for (int w0 = start; w0 < end; w0 += AGG_W) {
            int cnt = end - w0; if (cnt > AGG_W) cnt = AGG_W;
            __syncthreads();          // previous readers of al/sl/rl done
            // coalesced stage of a-values (512 floats) and metadata
#pragma unroll
            for (int c = 0; c < 4; ++c) {
                int fi = c * 128 + tid;        // 0..511
                int p = fi >> 3;
                if (p < cnt) al[p][fi & 7] = a_ws[(size_t)(w0 + p) * 8 + (fi & 7)];
            }
            if (tid < cnt) { sl[tid] = esrc_s[w0 + tid]; rl[tid] = ety_s[w0 + tid]; }
            __syncthreads();
            // window max (parallel over d-lanes, butterfly within 16-lane group)
            float wm = -1e30f;
            for (int j = d; j < cnt; j += 16) wm = fmaxf(wm, al[j][h]);
#pragma unroll
            for (int mset = 1; mset < 16; mset <<= 1)
                wm = fmaxf(wm, __shfl_xor(wm, mset, 16));
            float mnew = fmaxf(mrun, wm);
            float sf = __expf(mrun - mnew);
            den *= sf;
#pragma unroll
            for (int r = 0; r < R_TYPES; ++r) accR[r] *= sf;
            mrun = mnew;
            // gather & accumulate (independent loads, unrolled for MLP)
#pragma unroll 4
            for (int j = 0; j < cnt; ++j) {
                float ex = __expf(al[j][h] - mrun);
                den += ex;
                int s = sl[j];
                int r = rl[j];
                float exvv = ex * vbuf[(size_t)s * DIM + tid];
#pragma unroll
                for (int rr = 0; rr < R_TYPES; ++rr)
                    accR[rr] += (rr == r) ? exvv : 0.f;
            }
        }
        // bucket mix: one LDS round-trip, broadcast float4 reads, M from registers
        __syncthreads();
#pragma unroll
        for (int r = 0; r < R_TYPES; ++r) bl[r][tid] = accR[r];
        __syncthreads();
        float acc = 0.f;
#pragma unroll
        for (int r = 0; r < R_TYPES; ++r) {
            const float4* blr = (const float4*)&bl[r][h * 16];
#pragma unroll
            for (int dq = 0; dq < 4; ++dq) {
                float4 bv = blr[dq];
                acc = fmaf(bv.x, m_reg[r][dq * 4 + 0], acc);
                acc = fmaf(bv.y, m_reg[r][dq * 4 + 1], acc);
                acc = fmaf(bv.z, m_reg[r][dq * 4 + 2], acc);
                acc = fmaf(bv.w, m_reg[r][dq * 4 + 3], acc);
            }
        }
        hacc[(size_t)node * DIM + tid] = acc / fmaxf(den, 1e-9f);
    }
}

// ======================= K4: tiled Wa + gate + residual + LayerNorm ===========

__global__ __launch_bounds__(256) void k_final_gemm(
    const float* __restrict__ x, const int* __restrict__ nlist,
    const int* __restrict__ tile_type, const int* __restrict__ ntiles_g,
    const float* __restrict__ Wa, const float* __restrict__ skip,
    const float* __restrict__ gamma, const float* __restrict__ beta,
    float* __restrict__ out) {
    __shared__ float hs[BN][DIM];
    __shared__ float ys[BN][DIM];
    __shared__ int sids[BN];
    __shared__ float mred[BN], ired[BN];
    int b = blockIdx.x;
    if (b >= *ntiles_g) return;
    int tid = threadIdx.x;
    if (tid < BN) sids[tid] = nlist[b * BN + tid];
    __syncthreads();
    for (int idx = tid; idx < BN * DIM; idx += 256) {
        int row = idx >> 7, col = idx & 127;
        int nid = sids[row];
        hs[row][col] = (nid >= 0) ? out[(size_t)nid * DIM + col] : 0.f;
    }
    __syncthreads();
    int t = tile_type[b];
    int half = tid >> 7, col = tid & 127;
    const float* W = Wa + (size_t)t * DIM * DIM;
    float acc[8];
#pragma unroll
    for (int n = 0; n < 8; ++n) acc[n] = 0.f;
#pragma unroll 4
    for (int d = 0; d < DIM; ++d) {
        float w = W[d * DIM + col];
#pragma unroll
        for (int n = 0; n < 8; ++n) acc[n] = fmaf(hs[half * 8 + n][d], w, acc[n]);
    }
    float gte = 1.f / (1.f + __expf(-skip[t]));
#pragma unroll
    for (int n = 0; n < 8; ++n) {
        int row = half * 8 + n;
        int nid = sids[row];
        float xv = (nid >= 0) ? x[(size_t)nid * DIM + col] : 0.f;
        ys[row][col] = xv * (2.f - gte) + acc[n] * gte;
    }
    __syncthreads();
    int ng = tid >> 4, l16 = tid & 15;
    float s = 0.f, s2 = 0.f;
#pragma unroll
    for (int k2 = 0; k2 < 8; ++k2) {
        float yv = ys[ng][l16 + 16 * k2];
        s += yv; s2 += yv * yv;
    }
#pragma unroll
    for (int m = 1; m < 16; m <<= 1) {
        s  += __shfl_xor(s, m, 64);
        s2 += __shfl_xor(s2, m, 64);
    }
    if (l16 == 0) {
        float mu = s * (1.f / DIM);
        float var = s2 * (1.f / DIM) - mu * mu;
        mred[ng] = mu;
        ired[ng] = rsqrtf(var + 1e-5f);
    }
    __syncthreads();
    float gm = gamma[col], bt = beta[col];
#pragma unroll
    for (int n = 0; n < 8; ++n) {
        int row = half * 8 + n;
        int nid = sids[row];
        if (nid >= 0)
            out[(size_t)nid * DIM + col] = (ys[row][col] - mred[row]) * ired[row] * gm + bt;
    }
}

// ======================= launcher =======================

extern "C" void kernel_launch(void* const* d_in, const int* in_sizes, int n_in,
                              void* d_out, int out_size, void* d_ws, size_t ws_size,
                              hipStream_t stream) {
    const float* x       = (const float*)d_in[0];
    const int*   src     = (const int*)d_in[1];
    const int*   dst     = (const int*)d_in[2];
    const int*   ntype   = (const int*)d_in[3];
    const int*   etype   = (const int*)d_in[4];
    const float* Wk      = (const float*)d_in[5];
    const float* Wq      = (const float*)d_in[6];
    const float* Wv      = (const float*)d_in[7];
    const float* Wa      = (const float*)d_in[8];
    const float* rel_pri = (const float*)d_in[9];
    const float* rel_att = (const float*)d_in[10];
    const float* rel_msg = (const float*)d_in[11];
    const float* skip    = (const float*)d_in[12];
    const float* gamma   = (const float*)d_in[13];
    const float* beta    = (const float*)d_in[14];
    float* out = (float*)d_out;

    const int N = N_NODES, E = N_EDGES;

    // workspace layout
    char* ws = (char*)d_ws;
    float* kb   = (float*)ws;                          // N*128
    float* qb   = kb + (size_t)N * DIM;                // N*128
    float* vb   = qb + (size_t)N * DIM;                // N*128
    float* a_ws = vb + (size_t)N * DIM;                // E*8
    int* deg     = (int*)(a_ws + (size_t)E * H_HEADS); // N
    int* offs    = deg + N;                            // N
    int* esrc_s  = offs + N;                           // E
    int* edst_s  = esrc_s + E;                         // E
    int* ety_s   = edst_s + E;                         // E
    int* sp_src  = ety_s + E;                          // E
    int* sp_dst  = sp_src + E;                         // E
    int* sp_r    = sp_dst + E;                         // E
    int* sp_pos  = sp_r + E;                           // E
    int* rhist   = sp_pos + E;                         // R_TYPES*NBLK_E
    int* partial = rhist + R_TYPES * NBLK_E;           // 256
    int* tcnt    = partial + 256;                      // 4
    int* pbase   = tcnt + T_TYPES;                     // 4
    int* ntiles  = pbase + T_TYPES;                    // 1
    int* tile_type = ntiles + 1;                       // MAX_TILES
    int* nlist   = tile_type + MAX_TILES;              // MAX_TILES*BN
    int* wpos    = nlist + (size_t)MAX_TILES * BN;     // N

    const int nbScan = (N + 255) / 256;

    // CSR build (edges by dst), materializing sorted src/dst/etype
    hipMemsetAsync(deg, 0, (size_t)N * sizeof(int), stream);
    k_count<<<(E + 255) / 256, 256, 0, stream>>>(dst, deg, E);
    k_scanA<<<nbScan, 256, 0, stream>>>(deg, offs, partial, N);
    k_scanB<<<1, 256, 0, stream>>>(partial, nbScan);
    k_scanC<<<nbScan, 256, 0, stream>>>(offs, partial, N);
    k_scatter2<<<(E + 255) / 256, 256, 0, stream>>>(
        src, dst, etype, offs, esrc_s, edst_s, ety_s, E);

    // counting-sort CSR positions by relation type
    k_rhist<<<NBLK_E, 256, 0, stream>>>(ety_s, rhist, E);
    k_rscan<<<1, 256, 0, stream>>>(rhist, R_TYPES * NBLK_E);
    k_rscatter<<<NBLK_E, 256, 0, stream>>>(
        esrc_s, edst_s, ety_s, rhist, sp_src, sp_dst, sp_r, sp_pos, E);

    // node type buckets (padded 16-node tiles)
    hipMemsetAsync(tcnt, 0, T_TYPES * sizeof(int), stream);
    k_tcount_agg<<<nbScan, 256, 0, stream>>>(ntype, tcnt, wpos, N);
    k_tsetup<<<1, 256, 0, stream>>>(tcnt, pbase, ntiles, tile_type);
    hipMemsetAsync(nlist, 0xFF, (size_t)MAX_TILES * BN * sizeof(int), stream);
    k_tscatter2<<<nbScan, 256, 0, stream>>>(ntype, wpos, pbase, nlist, N);

    // projections (tiled per-type GEMM, 4 tiles/block, 4 cols/thread)
    k_kqv_gemm2<<<(MAX_TILES + 3) / 4, 384, 0, stream>>>(
        x, nlist, tile_type, ntiles, Wk, Wq, Wv, kb, qb, vb);

    // edge logits (r-sorted, conflict-free LDS)
    k_edge_a2<<<(E + 31) / 32, 256, 0, stream>>>(
        kb, qb, sp_src, sp_dst, sp_r, sp_pos, rel_att, rel_pri, a_ws, E);

    // per-node softmax + message aggregation -> d_out (scratch)
    k_aggregate4<<<4096, 128, 0, stream>>>(
        vb, a_ws, offs, deg, esrc_s, ety_s, rel_msg, out, N);

    // output projection + gate + residual + LayerNorm (in place on d_out)
    k_final_gemm<<<MAX_TILES, 256, 0, stream>>>(
        x, nlist, tile_type, ntiles, Wa, skip, gamma, beta, out);
}

// Round 7
// 480.183 us; speedup vs baseline: 1.1358x; 1.1358x over previous
//
#include <hip/hip_runtime.h>
#include <math.h>

#define N_NODES 50000
#define N_EDGES 400000
#define H_HEADS 8
#define D_HEAD 16
#define R_TYPES 6
#define T_TYPES 4
#define DIM 128
#define BN 16                                      // nodes per GEMM tile
#define MAX_TILES ((N_NODES + BN - 1) / BN + T_TYPES)
#define NBLK_E ((N_EDGES + 255) / 256)             // 1563
#define NKEYS (N_NODES * R_TYPES)                  // 300000 (dst,r) buckets
#define NBLK_K ((NKEYS + 255) / 256)               // 1172

// ======================= generic scan pieces =======================

__global__ void k_scanA(const int* __restrict__ cnt, int* __restrict__ offs,
                        int* __restrict__ partial, int n) {
    __shared__ int tmp[256];
    int tid = threadIdx.x;
    int i = blockIdx.x * 256 + tid;
    int v = (i < n) ? cnt[i] : 0;
    tmp[tid] = v;
    __syncthreads();
    for (int o = 1; o < 256; o <<= 1) {
        int t = (tid >= o) ? tmp[tid - o] : 0;
        __syncthreads();
        tmp[tid] += t;
        __syncthreads();
    }
    if (i < n) offs[i] = tmp[tid] - v;           // exclusive within block
    if (tid == 255) partial[blockIdx.x] = tmp[255];
}

// single-block chunked exclusive scan (arbitrary length)
__global__ void k_rscan(int* __restrict__ a, int total) {
    __shared__ int tmp[256];
    __shared__ int carry_s;
    int tid = threadIdx.x;
    if (tid == 0) carry_s = 0;
    __syncthreads();
    for (int base = 0; base < total; base += 256) {
        int i = base + tid;
        int v = (i < total) ? a[i] : 0;
        tmp[tid] = v;
        __syncthreads();
        for (int o = 1; o < 256; o <<= 1) {
            int t = (tid >= o) ? tmp[tid - o] : 0;
            __syncthreads();
            tmp[tid] += t;
            __syncthreads();
        }
        int carry = carry_s;
        if (i < total) a[i] = carry + tmp[tid] - v;   // exclusive
        __syncthreads();
        if (tid == 255) carry_s = carry + tmp[255];
        __syncthreads();
    }
}

__global__ void k_scanC(int* __restrict__ offs, const int* __restrict__ partial, int n) {
    int i = blockIdx.x * 256 + threadIdx.x;
    if (i < n) offs[i] += partial[blockIdx.x];
}

// ======================= (dst,r)-keyed CSR build =======================

__global__ void k_count6(const int* __restrict__ dst, const int* __restrict__ etype,
                         int* __restrict__ deg6, int n) {
    int e = blockIdx.x * blockDim.x + threadIdx.x;
    if (e < n) atomicAdd(&deg6[dst[e] * R_TYPES + etype[e]], 1);
}

__global__ void k_scatter6(const int* __restrict__ src, const int* __restrict__ dst,
                           const int* __restrict__ etype, int* __restrict__ cursor6,
                           int* __restrict__ esrc_s, int* __restrict__ edst_s,
                           int* __restrict__ ety_s, int n) {
    int e = blockIdx.x * blockDim.x + threadIdx.x;
    if (e < n) {
        int key = dst[e] * R_TYPES + etype[e];
        int pos = atomicAdd(&cursor6[key], 1);
        esrc_s[pos] = src[e];
        edst_s[pos] = dst[e];
        ety_s[pos]  = etype[e];
    }
}

// ======================= global r-sort of CSR positions ==============

__global__ void k_rhist(const int* __restrict__ ety_s, int* __restrict__ rcnt, int n) {
    __shared__ int h[R_TYPES];
    int tid = threadIdx.x;
    if (tid < R_TYPES) h[tid] = 0;
    __syncthreads();
    int i = blockIdx.x * 256 + tid;
    if (i < n) atomicAdd(&h[ety_s[i]], 1);
    __syncthreads();
    if (tid < R_TYPES) rcnt[tid * NBLK_E + blockIdx.x] = h[tid];
}

__global__ void k_rscatter(const int* __restrict__ esrc_s, const int* __restrict__ edst_s,
                           const int* __restrict__ ety_s, const int* __restrict__ rbase,
                           int* __restrict__ sp_src, int* __restrict__ sp_dst,
                           int* __restrict__ sp_r, int* __restrict__ sp_pos, int n) {
    __shared__ int hist[R_TYPES];
    __shared__ int base[R_TYPES];
    int tid = threadIdx.x;
    if (tid < R_TYPES) hist[tid] = 0;
    __syncthreads();
    int p = blockIdx.x * 256 + tid;
    int r = 0, rank = 0;
    if (p < n) {
        r = ety_s[p];
        rank = atomicAdd(&hist[r], 1);
    }
    __syncthreads();
    if (tid < R_TYPES) base[tid] = rbase[tid * NBLK_E + blockIdx.x];
    __syncthreads();
    if (p < n) {
        int q2 = base[r] + rank;
        sp_src[q2] = esrc_s[p];
        sp_dst[q2] = edst_s[p];
        sp_r[q2]   = r;
        sp_pos[q2] = p;
    }
}

// ======================= node type bucketing (padded 16-node tiles) ===========

__global__ void k_tcount_agg(const int* __restrict__ ntype, int* __restrict__ tcnt,
                             int* __restrict__ wpos, int n) {
    __shared__ int hist[T_TYPES];
    __shared__ int base[T_TYPES];
    int tid = threadIdx.x;
    if (tid < T_TYPES) hist[tid] = 0;
    __syncthreads();
    int i = blockIdx.x * 256 + tid;
    int t = 0, rank = 0;
    if (i < n) {
        t = ntype[i];
        rank = atomicAdd(&hist[t], 1);
    }
    __syncthreads();
    if (tid < T_TYPES)
        base[tid] = (hist[tid] > 0) ? atomicAdd(&tcnt[tid], hist[tid]) : 0;
    __syncthreads();
    if (i < n) wpos[i] = base[t] + rank;
}

__global__ void k_tsetup(const int* __restrict__ tcnt, int* __restrict__ pbase,
                         int* __restrict__ ntiles_g, int* __restrict__ tile_type) {
    __shared__ int off[T_TYPES + 1];
    if (threadIdx.x == 0) {
        int o = 0;
        for (int t = 0; t < T_TYPES; ++t) {
            off[t] = o;
            pbase[t] = o * BN;
            o += (tcnt[t] + BN - 1) / BN;
        }
        off[T_TYPES] = o;
        *ntiles_g = o;
    }
    __syncthreads();
    int total = off[T_TYPES];
    for (int i = threadIdx.x; i < total; i += blockDim.x) {
        int t = 0;
        while (t < T_TYPES - 1 && i >= off[t + 1]) ++t;
        tile_type[i] = t;
    }
}

__global__ void k_tscatter2(const int* __restrict__ ntype, const int* __restrict__ wpos,
                            const int* __restrict__ pbase, int* __restrict__ nlist, int n) {
    int i = blockIdx.x * 256 + threadIdx.x;
    if (i < n) nlist[pbase[ntype[i]] + wpos[i]] = i;
}

// ======================= K1: tiled typed-linear k,q,v =======================
// block = 4 tiles x (3 mats x 32 threads). Each thread: 4 cols x 16 nodes.

__global__ __launch_bounds__(384) void k_kqv_gemm2(
    const float* __restrict__ x, const int* __restrict__ nlist,
    const int* __restrict__ tile_type, const int* __restrict__ ntiles_g,
    const float* __restrict__ Wk, const float* __restrict__ Wq,
    const float* __restrict__ Wv,
    float* __restrict__ kb, float* __restrict__ qb, float* __restrict__ vb) {
    __shared__ float xs[4 * BN][DIM];   // 32 KB
    __shared__ int sids[4 * BN];
    int tid = threadIdx.x;
    int b = blockIdx.x;
    int nt = *ntiles_g;
    if (tid < 4 * BN) {
        int tb0 = b * 4 + (tid >> 4);
        sids[tid] = (tb0 < nt) ? nlist[tb0 * BN + (tid & 15)] : -1;
    }
    __syncthreads();
    for (int idx = tid; idx < 4 * BN * (DIM / 4); idx += 384) {
        int row = idx >> 5;
        int q4 = idx & 31;
        int nid = sids[row];
        float4 v4 = make_float4(0.f, 0.f, 0.f, 0.f);
        if (nid >= 0) v4 = *(const float4*)(x + (size_t)nid * DIM + q4 * 4);
        *(float4*)(&xs[row][q4 * 4]) = v4;
    }
    __syncthreads();
    int lt = tid / 96;            // local tile 0..3
    int wi = tid % 96;
    int mat = wi >> 5;            // 0=k 1=q 2=v
    int colq = wi & 31;
    int tb = b * 4 + lt;
    if (tb >= nt) return;
    int t = tile_type[tb];
    const float* W = (mat == 0 ? Wk : (mat == 1 ? Wq : Wv))
                     + (size_t)t * DIM * DIM + colq * 4;
    float acc[BN][4];
#pragma unroll
    for (int n = 0; n < BN; ++n) {
        acc[n][0] = 0.f; acc[n][1] = 0.f; acc[n][2] = 0.f; acc[n][3] = 0.f;
    }
    const float* xbase = &xs[lt * BN][0];
    for (int dq = 0; dq < 32; ++dq) {
        float4 w0 = *(const float4*)(W + (size_t)(dq * 4 + 0) * DIM);
        float4 w1 = *(const float4*)(W + (size_t)(dq * 4 + 1) * DIM);
        float4 w2 = *(const float4*)(W + (size_t)(dq * 4 + 2) * DIM);
        float4 w3 = *(const float4*)(W + (size_t)(dq * 4 + 3) * DIM);
#pragma unroll
        for (int n = 0; n < BN; ++n) {
            float4 xv = *(const float4*)(xbase + n * DIM + dq * 4);
            acc[n][0] = fmaf(xv.x, w0.x, acc[n][0]);
            acc[n][0] = fmaf(xv.y, w1.x, acc[n][0]);
            acc[n][0] = fmaf(xv.z, w2.x, acc[n][0]);
            acc[n][0] = fmaf(xv.w, w3.x, acc[n][0]);
            acc[n][1] = fmaf(xv.x, w0.y, acc[n][1]);
            acc[n][1] = fmaf(xv.y, w1.y, acc[n][1]);
            acc[n][1] = fmaf(xv.z, w2.y, acc[n][1]);
            acc[n][1] = fmaf(xv.w, w3.y, acc[n][1]);
            acc[n][2] = fmaf(xv.x, w0.z, acc[n][2]);
            acc[n][2] = fmaf(xv.y, w1.z, acc[n][2]);
            acc[n][2] = fmaf(xv.z, w2.z, acc[n][2]);
            acc[n][2] = fmaf(xv.w, w3.z, acc[n][2]);
            acc[n][3] = fmaf(xv.x, w0.w, acc[n][3]);
            acc[n][3] = fmaf(xv.y, w1.w, acc[n][3]);
            acc[n][3] = fmaf(xv.z, w2.w, acc[n][3]);
            acc[n][3] = fmaf(xv.w, w3.w, acc[n][3]);
        }
    }
    float* ob = (mat == 0 ? kb : (mat == 1 ? qb : vb));
#pragma unroll
    for (int n = 0; n < BN; ++n) {
        int nid = sids[lt * BN + n];
        if (nid >= 0)
            *(float4*)(ob + (size_t)nid * DIM + colq * 4) =
                make_float4(acc[n][0], acc[n][1], acc[n][2], acc[n][3]);
    }
}

// ======================= K2: per-edge attention logits (r-sorted) =============

__global__ __launch_bounds__(256) void k_edge_a2(
    const float* __restrict__ kbuf, const float* __restrict__ qbuf,
    const int* __restrict__ sp_src, const int* __restrict__ sp_dst,
    const int* __restrict__ sp_r, const int* __restrict__ sp_pos,
    const float* __restrict__ rel_att, const float* __restrict__ rel_pri,
    float* __restrict__ a_ws, int nE) {
    __shared__ float A2[2][8 * 260];   // 2 r-slots, 8 heads, 16x16 each (stride 260)
    __shared__ float pri[2][8];
    __shared__ int r01[2];
    int b = blockIdx.x;
    int e0 = b * 32;
    int tid = threadIdx.x;
    int nHere = nE - e0; if (nHere > 32) nHere = 32;
    if (nHere <= 0) return;
    if (tid == 0) { r01[0] = sp_r[e0]; r01[1] = sp_r[e0 + nHere - 1]; }
    __syncthreads();
    int r0 = r01[0], r1 = r01[1];
    for (int idx = tid; idx < 2 * 2048; idx += 256) {
        int slot = idx >> 11;
        if (slot == 1 && r1 == r0) break;
        int rem = idx & 2047;
        int h = rem >> 8, dj = rem & 255;
        int rr = slot ? r1 : r0;
        A2[slot][h * 260 + dj] = rel_att[(h * R_TYPES + rr) * 256 + dj];
    }
    if (tid < 16) {
        int slot = tid >> 3, h = tid & 7;
        pri[slot][h] = rel_pri[h * R_TYPES + (slot ? r1 : r0)] * 0.25f;
    }
    __syncthreads();
    int el = tid >> 3;
    int h  = tid & 7;
    int q2 = e0 + el;
    if (q2 >= nE) return;
    int s = sp_src[q2], dn = sp_dst[q2], r = sp_r[q2];
    int slot = (r == r0) ? 0 : 1;
    const float4* kp = (const float4*)(kbuf + (size_t)s  * DIM + h * 16);
    const float4* qp = (const float4*)(qbuf + (size_t)dn * DIM + h * 16);
    float4 k4[4], q4[4];
#pragma unroll
    for (int i = 0; i < 4; ++i) { k4[i] = kp[i]; q4[i] = qp[i]; }
    float kk[16] = {k4[0].x,k4[0].y,k4[0].z,k4[0].w, k4[1].x,k4[1].y,k4[1].z,k4[1].w,
                    k4[2].x,k4[2].y,k4[2].z,k4[2].w, k4[3].x,k4[3].y,k4[3].z,k4[3].w};
    float qq[16] = {q4[0].x,q4[0].y,q4[0].z,q4[0].w, q4[1].x,q4[1].y,q4[1].z,q4[1].w,
                    q4[2].x,q4[2].y,q4[2].z,q4[2].w, q4[3].x,q4[3].y,q4[3].z,q4[3].w};
    const float4* A4 = (const float4*)&A2[slot][h * 260];
    float accj[16];
#pragma unroll
    for (int j = 0; j < 16; ++j) accj[j] = 0.f;
#pragma unroll
    for (int d = 0; d < 16; ++d) {
        float kd = kk[d];
#pragma unroll
        for (int jj = 0; jj < 4; ++jj) {
            float4 a4 = A4[d * 4 + jj];
            accj[jj * 4 + 0] = fmaf(kd, a4.x, accj[jj * 4 + 0]);
            accj[jj * 4 + 1] = fmaf(kd, a4.y, accj[jj * 4 + 1]);
            accj[jj * 4 + 2] = fmaf(kd, a4.z, accj[jj * 4 + 2]);
            accj[jj * 4 + 3] = fmaf(kd, a4.w, accj[jj * 4 + 3]);
        }
    }
    float acc = 0.f;
#pragma unroll
    for (int j = 0; j < 16; ++j) acc = fmaf(accj[j], qq[j], acc);
    a_ws[(size_t)sp_pos[q2] * 8 + h] = acc * pri[slot][h];
}

// ======================= K3: per-node softmax + aggregation (v5) ==============
// 128 threads per node, 2 nodes per 256-block (agg3 structure). The CSR is
// (dst,r)-keyed so each node's segment is 6 contiguous r-runs with boundaries
// beg6[n*6+r]: per run accumulate into ONE register, flush once via ds_write.
// No 6-way select chain, no LDS RMW.

__global__ __launch_bounds__(256) void k_aggregate5(
    const float* __restrict__ vbuf, const float* __restrict__ a_ws,
    const int* __restrict__ beg6, const int* __restrict__ esrc_s,
    const float* __restrict__ rel_msg,
    float* __restrict__ hacc, int n, int nE) {
    __shared__ float wsum[2][R_TYPES * 128];   // 6 KB
    __shared__ int bounds[2][R_TYPES + 1];
    int tid = threadIdx.x;
    int nb = tid >> 7;
    int lane2 = tid & 127;
    int node = blockIdx.x * 2 + nb;
    bool valid = node < n;
    int h = lane2 >> 4;
    int d = lane2 & 15;
    if (lane2 <= R_TYPES) {
        int idx = node * R_TYPES + lane2;
        bounds[nb][lane2] = valid ? ((idx < n * R_TYPES) ? beg6[idx] : nE) : 0;
    }
    __syncthreads();
    int start = bounds[nb][0];
    int end   = bounds[nb][R_TYPES];

    // pass 1: parallel max across d-lanes (coalesced 512B per 16-edge chunk)
    float mmax = -1e30f;
    for (int p = start + d; p < end; p += 16)
        mmax = fmaxf(mmax, a_ws[(size_t)p * 8 + h]);
#pragma unroll
    for (int mask = 1; mask < 16; mask <<= 1)
        mmax = fmaxf(mmax, __shfl_xor(mmax, mask, 64));

    // zero my bucket slots (overwritten by flush for non-empty runs)
    float* wsn = &wsum[nb][0];
#pragma unroll
    for (int rr = 0; rr < R_TYPES; ++rr) wsn[rr * 128 + lane2] = 0.f;

    // pass 2: per-r-run register accumulation, one flush per run
    float den = 0.f;
#pragma unroll
    for (int rr = 0; rr < R_TYPES; ++rr) {
        int b0 = bounds[nb][rr], b1 = bounds[nb][rr + 1];
        if (b0 == b1) continue;                  // wave-uniform branch
        float racc = 0.f;
        for (int p = b0; p < b1; ++p) {
            float av = a_ws[(size_t)p * 8 + h];  // broadcast within h-group
            float ex = __expf(av - mmax);
            den += ex;
            int s = esrc_s[p];                   // wave-broadcast load
            racc = fmaf(ex, vbuf[(size_t)s * DIM + lane2], racc);
        }
        wsn[rr * 128 + lane2] = racc;
    }
    __syncthreads();

    // epilogue: out[h][d] = (1/den) * sum_r sum_dp bucket[r][h][dp] * M[h][r][dp][d]
    float acc = 0.f;
#pragma unroll
    for (int rr = 0; rr < R_TYPES; ++rr) {
        const float*  M   = rel_msg + ((size_t)h * R_TYPES + rr) * 256;
        const float4* blr = (const float4*)&wsn[rr * 128 + h * 16];
#pragma unroll
        for (int dq = 0; dq < 4; ++dq) {
            float4 bv = blr[dq];
            acc = fmaf(bv.x, M[(dq * 4 + 0) * 16 + d], acc);
            acc = fmaf(bv.y, M[(dq * 4 + 1) * 16 + d], acc);
            acc = fmaf(bv.z, M[(dq * 4 + 2) * 16 + d], acc);
            acc = fmaf(bv.w, M[(dq * 4 + 3) * 16 + d], acc);
        }
    }
    if (valid)
        hacc[(size_t)node * DIM + lane2] = acc / fmaxf(den, 1e-9f);
}

// ======================= K4: tiled Wa + gate + residual + LayerNorm ===========

__global__ __launch_bounds__(256) void k_final_gemm(
    const float* __restrict__ x, const int* __restrict__ nlist,
    const int* __restrict__ tile_type, const int* __restrict__ ntiles_g,
    const float* __restrict__ Wa, const float* __restrict__ skip,
    const float* __restrict__ gamma, const float* __restrict__ beta,
    float* __restrict__ out) {
    __shared__ float hs[BN][DIM];
    __shared__ float ys[BN][DIM];
    __shared__ int sids[BN];
    __shared__ float mred[BN], ired[BN];
    int b = blockIdx.x;
    if (b >= *ntiles_g) return;
    int tid = threadIdx.x;
    if (tid < BN) sids[tid] = nlist[b * BN + tid];
    __syncthreads();
    for (int idx = tid; idx < BN * DIM; idx += 256) {
        int row = idx >> 7, col = idx & 127;
        int nid = sids[row];
        hs[row][col] = (nid >= 0) ? out[(size_t)nid * DIM + col] : 0.f;
    }
    __syncthreads();
    int t = tile_type[b];
    int half = tid >> 7, col = tid & 127;
    const float* W = Wa + (size_t)t * DIM * DIM;
    float acc[8];
#pragma unroll
    for (int n = 0; n < 8; ++n) acc[n] = 0.f;
#pragma unroll 4
    for (int d = 0; d < DIM; ++d) {
        float w = W[d * DIM + col];
#pragma unroll
        for (int n = 0; n < 8; ++n) acc[n] = fmaf(hs[half * 8 + n][d], w, acc[n]);
    }
    float gte = 1.f / (1.f + __expf(-skip[t]));
#pragma unroll
    for (int n = 0; n < 8; ++n) {
        int row = half * 8 + n;
        int nid = sids[row];
        float xv = (nid >= 0) ? x[(size_t)nid * DIM + col] : 0.f;
        ys[row][col] = xv * (2.f - gte) + acc[n] * gte;
    }
    __syncthreads();
    int ng = tid >> 4, l16 = tid & 15;
    float s = 0.f, s2 = 0.f;
#pragma unroll
    for (int k2 = 0; k2 < 8; ++k2) {
        float yv = ys[ng][l16 + 16 * k2];
        s += yv; s2 += yv * yv;
    }
#pragma unroll
    for (int m = 1; m < 16; m <<= 1) {
        s  += __shfl_xor(s, m, 64);
        s2 += __shfl_xor(s2, m, 64);
    }
    if (l16 == 0) {
        float mu = s * (1.f / DIM);
        float var = s2 * (1.f / DIM) - mu * mu;
        mred[ng] = mu;
        ired[ng] = rsqrtf(var + 1e-5f);
    }
    __syncthreads();
    float gm = gamma[col], bt = beta[col];
#pragma unroll
    for (int n = 0; n < 8; ++n) {
        int row = half * 8 + n;
        int nid = sids[row];
        if (nid >= 0)
            out[(size_t)nid * DIM + col] = (ys[row][col] - mred[row]) * ired[row] * gm + bt;
    }
}

// ======================= launcher =======================

extern "C" void kernel_launch(void* const* d_in, const int* in_sizes, int n_in,
                              void* d_out, int out_size, void* d_ws, size_t ws_size,
                              hipStream_t stream) {
    const float* x       = (const float*)d_in[0];
    const int*   src     = (const int*)d_in[1];
    const int*   dst     = (const int*)d_in[2];
    const int*   ntype   = (const int*)d_in[3];
    const int*   etype   = (const int*)d_in[4];
    const float* Wk      = (const float*)d_in[5];
    const float* Wq      = (const float*)d_in[6];
    const float* Wv      = (const float*)d_in[7];
    const float* Wa      = (const float*)d_in[8];
    const float* rel_pri = (const float*)d_in[9];
    const float* rel_att = (const float*)d_in[10];
    const float* rel_msg = (const float*)d_in[11];
    const float* skip    = (const float*)d_in[12];
    const float* gamma   = (const float*)d_in[13];
    const float* beta    = (const float*)d_in[14];
    float* out = (float*)d_out;

    const int N = N_NODES, E = N_EDGES;

    // workspace layout
    char* ws = (char*)d_ws;
    float* kb   = (float*)ws;                          // N*128
    float* qb   = kb + (size_t)N * DIM;                // N*128
    float* vb   = qb + (size_t)N * DIM;                // N*128
    float* a_ws = vb + (size_t)N * DIM;                // E*8
    int* deg6    = (int*)(a_ws + (size_t)E * H_HEADS); // NKEYS
    int* beg6    = deg6 + NKEYS;                       // NKEYS
    int* cursor6 = beg6 + NKEYS;                       // NKEYS
    int* partial6 = cursor6 + NKEYS;                   // NBLK_K
    int* esrc_s  = partial6 + NBLK_K;                  // E
    int* edst_s  = esrc_s + E;                         // E
    int* ety_s   = edst_s + E;                         // E
    int* sp_src  = ety_s + E;                          // E
    int* sp_dst  = sp_src + E;                         // E
    int* sp_r    = sp_dst + E;                         // E
    int* sp_pos  = sp_r + E;                           // E
    int* rhist   = sp_pos + E;                         // R_TYPES*NBLK_E
    int* tcnt    = rhist + R_TYPES * NBLK_E;           // 4
    int* pbase   = tcnt + T_TYPES;                     // 4
    int* ntiles  = pbase + T_TYPES;                    // 1
    int* tile_type = ntiles + 1;                       // MAX_TILES
    int* nlist   = tile_type + MAX_TILES;              // MAX_TILES*BN
    int* wpos    = nlist + (size_t)MAX_TILES * BN;     // N

    const int nbScan = (N + 255) / 256;

    // (dst,r)-keyed CSR build
    hipMemsetAsync(deg6, 0, (size_t)NKEYS * sizeof(int), stream);
    k_count6<<<(E + 255) / 256, 256, 0, stream>>>(dst, etype, deg6, E);
    k_scanA<<<NBLK_K, 256, 0, stream>>>(deg6, beg6, partial6, NKEYS);
    k_rscan<<<1, 256, 0, stream>>>(partial6, NBLK_K);
    k_scanC<<<NBLK_K, 256, 0, stream>>>(beg6, partial6, NKEYS);
    hipMemcpyAsync(cursor6, beg6, (size_t)NKEYS * sizeof(int),
                   hipMemcpyDeviceToDevice, stream);
    k_scatter6<<<(E + 255) / 256, 256, 0, stream>>>(
        src, dst, etype, cursor6, esrc_s, edst_s, ety_s, E);

    // global counting-sort of CSR positions by relation type (for k_edge_a2)
    k_rhist<<<NBLK_E, 256, 0, stream>>>(ety_s, rhist, E);
    k_rscan<<<1, 256, 0, stream>>>(rhist, R_TYPES * NBLK_E);
    k_rscatter<<<NBLK_E, 256, 0, stream>>>(
        esrc_s, edst_s, ety_s, rhist, sp_src, sp_dst, sp_r, sp_pos, E);

    // node type buckets (padded 16-node tiles)
    hipMemsetAsync(tcnt, 0, T_TYPES * sizeof(int), stream);
    k_tcount_agg<<<nbScan, 256, 0, stream>>>(ntype, tcnt, wpos, N);
    k_tsetup<<<1, 256, 0, stream>>>(tcnt, pbase, ntiles, tile_type);
    hipMemsetAsync(nlist, 0xFF, (size_t)MAX_TILES * BN * sizeof(int), stream);
    k_tscatter2<<<nbScan, 256, 0, stream>>>(ntype, wpos, pbase, nlist, N);

    // projections (tiled per-type GEMM, 4 tiles/block, 4 cols/thread)
    k_kqv_gemm2<<<(MAX_TILES + 3) / 4, 384, 0, stream>>>(
        x, nlist, tile_type, ntiles, Wk, Wq, Wv, kb, qb, vb);

    // edge logits (r-sorted, conflict-free LDS)
    k_edge_a2<<<(E + 31) / 32, 256, 0, stream>>>(
        kb, qb, sp_src, sp_dst, sp_r, sp_pos, rel_att, rel_pri, a_ws, E);

    // per-node softmax + message aggregation -> d_out (scratch)
    k_aggregate5<<<(N + 1) / 2, 256, 0, stream>>>(
        vb, a_ws, beg6, esrc_s, rel_msg, out, N, E);

    // output projection + gate + residual + LayerNorm (in place on d_out)
    k_final_gemm<<<MAX_TILES, 256, 0, stream>>>(
        x, nlist, tile_type, ntiles, Wa, skip, gamma, beta, out);
}

// Round 8
// 453.310 us; speedup vs baseline: 1.2031x; 1.0593x over previous
//
#include <hip/hip_runtime.h>
#include <math.h>

#define N_NODES 50000
#define N_EDGES 400000
#define H_HEADS 8
#define D_HEAD 16
#define R_TYPES 6
#define T_TYPES 4
#define DIM 128
#define BN 16                                      // nodes per GEMM tile
#define MAX_TILES ((N_NODES + BN - 1) / BN + T_TYPES)
#define NBLK_E ((N_EDGES + 255) / 256)             // 1563
#define NKEYS (N_NODES * R_TYPES)                  // 300000 (dst,r) buckets
#define NBLK_K ((NKEYS + 255) / 256)               // 1172
#define SM_SHIFT 8.0f                              // constant softmax shift

// ======================= generic scan pieces =======================

__global__ void k_scanA(const int* __restrict__ cnt, int* __restrict__ offs,
                        int* __restrict__ partial, int n) {
    __shared__ int tmp[256];
    int tid = threadIdx.x;
    int i = blockIdx.x * 256 + tid;
    int v = (i < n) ? cnt[i] : 0;
    tmp[tid] = v;
    __syncthreads();
    for (int o = 1; o < 256; o <<= 1) {
        int t = (tid >= o) ? tmp[tid - o] : 0;
        __syncthreads();
        tmp[tid] += t;
        __syncthreads();
    }
    if (i < n) offs[i] = tmp[tid] - v;           // exclusive within block
    if (tid == 255) partial[blockIdx.x] = tmp[255];
}

// single-block chunked exclusive scan (arbitrary length)
__global__ void k_rscan(int* __restrict__ a, int total) {
    __shared__ int tmp[256];
    __shared__ int carry_s;
    int tid = threadIdx.x;
    if (tid == 0) carry_s = 0;
    __syncthreads();
    for (int base = 0; base < total; base += 256) {
        int i = base + tid;
        int v = (i < total) ? a[i] : 0;
        tmp[tid] = v;
        __syncthreads();
        for (int o = 1; o < 256; o <<= 1) {
            int t = (tid >= o) ? tmp[tid - o] : 0;
            __syncthreads();
            tmp[tid] += t;
            __syncthreads();
        }
        int carry = carry_s;
        if (i < total) a[i] = carry + tmp[tid] - v;   // exclusive
        __syncthreads();
        if (tid == 255) carry_s = carry + tmp[255];
        __syncthreads();
    }
}

__global__ void k_scanC(int* __restrict__ offs, const int* __restrict__ partial, int n) {
    int i = blockIdx.x * 256 + threadIdx.x;
    if (i < n) offs[i] += partial[blockIdx.x];
}

// ======================= (dst,r)-keyed CSR build =======================

__global__ void k_count6(const int* __restrict__ dst, const int* __restrict__ etype,
                         int* __restrict__ deg6, int n) {
    int e = blockIdx.x * blockDim.x + threadIdx.x;
    if (e < n) atomicAdd(&deg6[dst[e] * R_TYPES + etype[e]], 1);
}

__global__ void k_scatter6(const int* __restrict__ src, const int* __restrict__ dst,
                           const int* __restrict__ etype, int* __restrict__ cursor6,
                           int* __restrict__ esrc_s, int* __restrict__ edst_s,
                           int* __restrict__ ety_s, int n) {
    int e = blockIdx.x * blockDim.x + threadIdx.x;
    if (e < n) {
        int key = dst[e] * R_TYPES + etype[e];
        int pos = atomicAdd(&cursor6[key], 1);
        esrc_s[pos] = src[e];
        edst_s[pos] = dst[e];
        ety_s[pos]  = etype[e];
    }
}

// ======================= global r-sort of CSR positions ==============

__global__ void k_rhist(const int* __restrict__ ety_s, int* __restrict__ rcnt, int n) {
    __shared__ int h[R_TYPES];
    int tid = threadIdx.x;
    if (tid < R_TYPES) h[tid] = 0;
    __syncthreads();
    int i = blockIdx.x * 256 + tid;
    if (i < n) atomicAdd(&h[ety_s[i]], 1);
    __syncthreads();
    if (tid < R_TYPES) rcnt[tid * NBLK_E + blockIdx.x] = h[tid];
}

__global__ void k_rscatter(const int* __restrict__ esrc_s, const int* __restrict__ edst_s,
                           const int* __restrict__ ety_s, const int* __restrict__ rbase,
                           int* __restrict__ sp_src, int* __restrict__ sp_dst,
                           int* __restrict__ sp_r, int* __restrict__ sp_pos, int n) {
    __shared__ int hist[R_TYPES];
    __shared__ int base[R_TYPES];
    int tid = threadIdx.x;
    if (tid < R_TYPES) hist[tid] = 0;
    __syncthreads();
    int p = blockIdx.x * 256 + tid;
    int r = 0, rank = 0;
    if (p < n) {
        r = ety_s[p];
        rank = atomicAdd(&hist[r], 1);
    }
    __syncthreads();
    if (tid < R_TYPES) base[tid] = rbase[tid * NBLK_E + blockIdx.x];
    __syncthreads();
    if (p < n) {
        int q2 = base[r] + rank;
        sp_src[q2] = esrc_s[p];
        sp_dst[q2] = edst_s[p];
        sp_r[q2]   = r;
        sp_pos[q2] = p;
    }
}

// ======================= node type bucketing (padded 16-node tiles) ===========

__global__ void k_tcount_agg(const int* __restrict__ ntype, int* __restrict__ tcnt,
                             int* __restrict__ wpos, int n) {
    __shared__ int hist[T_TYPES];
    __shared__ int base[T_TYPES];
    int tid = threadIdx.x;
    if (tid < T_TYPES) hist[tid] = 0;
    __syncthreads();
    int i = blockIdx.x * 256 + tid;
    int t = 0, rank = 0;
    if (i < n) {
        t = ntype[i];
        rank = atomicAdd(&hist[t], 1);
    }
    __syncthreads();
    if (tid < T_TYPES)
        base[tid] = (hist[tid] > 0) ? atomicAdd(&tcnt[tid], hist[tid]) : 0;
    __syncthreads();
    if (i < n) wpos[i] = base[t] + rank;
}

__global__ void k_tsetup(const int* __restrict__ tcnt, int* __restrict__ pbase,
                         int* __restrict__ ntiles_g, int* __restrict__ tile_type) {
    __shared__ int off[T_TYPES + 1];
    if (threadIdx.x == 0) {
        int o = 0;
        for (int t = 0; t < T_TYPES; ++t) {
            off[t] = o;
            pbase[t] = o * BN;
            o += (tcnt[t] + BN - 1) / BN;
        }
        off[T_TYPES] = o;
        *ntiles_g = o;
    }
    __syncthreads();
    int total = off[T_TYPES];
    for (int i = threadIdx.x; i < total; i += blockDim.x) {
        int t = 0;
        while (t < T_TYPES - 1 && i >= off[t + 1]) ++t;
        tile_type[i] = t;
    }
}

__global__ void k_tscatter2(const int* __restrict__ ntype, const int* __restrict__ wpos,
                            const int* __restrict__ pbase, int* __restrict__ nlist, int n) {
    int i = blockIdx.x * 256 + threadIdx.x;
    if (i < n) nlist[pbase[ntype[i]] + wpos[i]] = i;
}

// ======================= K1: tiled typed-linear k,q,v (v3) =======================
// One 16-node tile per block, 192 threads = 2 node-halves x 3 mats x 32 col-quads.
// Each thread: 8 nodes x 4 cols. Grid = 3129 blocks (600K threads, saturates chip)
// -- v2's fatal flaw was 79 blocks (half the SIMDs idle).

__global__ __launch_bounds__(192) void k_kqv_gemm3(
    const float* __restrict__ x, const int* __restrict__ nlist,
    const int* __restrict__ tile_type, const int* __restrict__ ntiles_g,
    const float* __restrict__ Wk, const float* __restrict__ Wq,
    const float* __restrict__ Wv,
    float* __restrict__ kb, float* __restrict__ qb, float* __restrict__ vb) {
    __shared__ float xs[BN][DIM];   // 8 KB
    __shared__ int sids[BN];
    int b = blockIdx.x;
    if (b >= *ntiles_g) return;
    int tid = threadIdx.x;
    if (tid < BN) sids[tid] = nlist[b * BN + tid];
    __syncthreads();
    for (int idx = tid; idx < BN * (DIM / 4); idx += 192) {
        int row = idx >> 5;
        int q4 = idx & 31;
        int nid = sids[row];
        float4 v4 = make_float4(0.f, 0.f, 0.f, 0.f);
        if (nid >= 0) v4 = *(const float4*)(x + (size_t)nid * DIM + q4 * 4);
        *(float4*)(&xs[row][q4 * 4]) = v4;
    }
    __syncthreads();
    int lt = tid / 96;            // node half: rows lt*8 .. lt*8+7
    int wi = tid % 96;
    int mat = wi >> 5;            // 0=k 1=q 2=v
    int colq = wi & 31;
    int t = tile_type[b];
    const float* W = (mat == 0 ? Wk : (mat == 1 ? Wq : Wv))
                     + (size_t)t * DIM * DIM + colq * 4;
    float acc[8][4];
#pragma unroll
    for (int n = 0; n < 8; ++n) {
        acc[n][0] = 0.f; acc[n][1] = 0.f; acc[n][2] = 0.f; acc[n][3] = 0.f;
    }
    const float* xbase = &xs[lt * 8][0];
    for (int dq = 0; dq < 32; ++dq) {
        float4 w0 = *(const float4*)(W + (size_t)(dq * 4 + 0) * DIM);
        float4 w1 = *(const float4*)(W + (size_t)(dq * 4 + 1) * DIM);
        float4 w2 = *(const float4*)(W + (size_t)(dq * 4 + 2) * DIM);
        float4 w3 = *(const float4*)(W + (size_t)(dq * 4 + 3) * DIM);
#pragma unroll
        for (int n = 0; n < 8; ++n) {
            float4 xv = *(const float4*)(xbase + n * DIM + dq * 4);
            acc[n][0] = fmaf(xv.x, w0.x, acc[n][0]);
            acc[n][0] = fmaf(xv.y, w1.x, acc[n][0]);
            acc[n][0] = fmaf(xv.z, w2.x, acc[n][0]);
            acc[n][0] = fmaf(xv.w, w3.x, acc[n][0]);
            acc[n][1] = fmaf(xv.x, w0.y, acc[n][1]);
            acc[n][1] = fmaf(xv.y, w1.y, acc[n][1]);
            acc[n][1] = fmaf(xv.z, w2.y, acc[n][1]);
            acc[n][1] = fmaf(xv.w, w3.y, acc[n][1]);
            acc[n][2] = fmaf(xv.x, w0.z, acc[n][2]);
            acc[n][2] = fmaf(xv.y, w1.z, acc[n][2]);
            acc[n][2] = fmaf(xv.z, w2.z, acc[n][2]);
            acc[n][2] = fmaf(xv.w, w3.z, acc[n][2]);
            acc[n][3] = fmaf(xv.x, w0.w, acc[n][3]);
            acc[n][3] = fmaf(xv.y, w1.w, acc[n][3]);
            acc[n][3] = fmaf(xv.z, w2.w, acc[n][3]);
            acc[n][3] = fmaf(xv.w, w3.w, acc[n][3]);
        }
    }
    float* ob = (mat == 0 ? kb : (mat == 1 ? qb : vb));
#pragma unroll
    for (int n = 0; n < 8; ++n) {
        int nid = sids[lt * 8 + n];
        if (nid >= 0)
            *(float4*)(ob + (size_t)nid * DIM + colq * 4) =
                make_float4(acc[n][0], acc[n][1], acc[n][2], acc[n][3]);
    }
}

// ======================= K2: per-edge attention logits (r-sorted) =============

__global__ __launch_bounds__(256) void k_edge_a2(
    const float* __restrict__ kbuf, const float* __restrict__ qbuf,
    const int* __restrict__ sp_src, const int* __restrict__ sp_dst,
    const int* __restrict__ sp_r, const int* __restrict__ sp_pos,
    const float* __restrict__ rel_att, const float* __restrict__ rel_pri,
    float* __restrict__ a_ws, int nE) {
    __shared__ float A2[2][8 * 260];   // 2 r-slots, 8 heads, 16x16 each (stride 260)
    __shared__ float pri[2][8];
    __shared__ int r01[2];
    int b = blockIdx.x;
    int e0 = b * 32;
    int tid = threadIdx.x;
    int nHere = nE - e0; if (nHere > 32) nHere = 32;
    if (nHere <= 0) return;
    if (tid == 0) { r01[0] = sp_r[e0]; r01[1] = sp_r[e0 + nHere - 1]; }
    __syncthreads();
    int r0 = r01[0], r1 = r01[1];
    for (int idx = tid; idx < 2 * 2048; idx += 256) {
        int slot = idx >> 11;
        if (slot == 1 && r1 == r0) break;
        int rem = idx & 2047;
        int h = rem >> 8, dj = rem & 255;
        int rr = slot ? r1 : r0;
        A2[slot][h * 260 + dj] = rel_att[(h * R_TYPES + rr) * 256 + dj];
    }
    if (tid < 16) {
        int slot = tid >> 3, h = tid & 7;
        pri[slot][h] = rel_pri[h * R_TYPES + (slot ? r1 : r0)] * 0.25f;
    }
    __syncthreads();
    int el = tid >> 3;
    int h  = tid & 7;
    int q2 = e0 + el;
    if (q2 >= nE) return;
    int s = sp_src[q2], dn = sp_dst[q2], r = sp_r[q2];
    int slot = (r == r0) ? 0 : 1;
    const float4* kp = (const float4*)(kbuf + (size_t)s  * DIM + h * 16);
    const float4* qp = (const float4*)(qbuf + (size_t)dn * DIM + h * 16);
    float4 k4[4], q4[4];
#pragma unroll
    for (int i = 0; i < 4; ++i) { k4[i] = kp[i]; q4[i] = qp[i]; }
    float kk[16] = {k4[0].x,k4[0].y,k4[0].z,k4[0].w, k4[1].x,k4[1].y,k4[1].z,k4[1].w,
                    k4[2].x,k4[2].y,k4[2].z,k4[2].w, k4[3].x,k4[3].y,k4[3].z,k4[3].w};
    float qq[16] = {q4[0].x,q4[0].y,q4[0].z,q4[0].w, q4[1].x,q4[1].y,q4[1].z,q4[1].w,
                    q4[2].x,q4[2].y,q4[2].z,q4[2].w, q4[3].x,q4[3].y,q4[3].z,q4[3].w};
    const float4* A4 = (const float4*)&A2[slot][h * 260];
    float accj[16];
#pragma unroll
    for (int j = 0; j < 16; ++j) accj[j] = 0.f;
#pragma unroll
    for (int d = 0; d < 16; ++d) {
        float kd = kk[d];
#pragma unroll
        for (int jj = 0; jj < 4; ++jj) {
            float4 a4 = A4[d * 4 + jj];
            accj[jj * 4 + 0] = fmaf(kd, a4.x, accj[jj * 4 + 0]);
            accj[jj * 4 + 1] = fmaf(kd, a4.y, accj[jj * 4 + 1]);
            accj[jj * 4 + 2] = fmaf(kd, a4.z, accj[jj * 4 + 2]);
            accj[jj * 4 + 3] = fmaf(kd, a4.w, accj[jj * 4 + 3]);
        }
    }
    float acc = 0.f;
#pragma unroll
    for (int j = 0; j < 16; ++j) acc = fmaf(accj[j], qq[j], acc);
    a_ws[(size_t)sp_pos[q2] * 8 + h] = acc * pri[slot][h];
}

// ======================= K3: per-node softmax + aggregation (v6) ==============
// Single pass: softmax is shift-invariant, so use constant shift SM_SHIFT
// instead of the segment max (logit std ~1.3 -> no overflow possible).
// Saves a full a_ws read + the serial max loop. (dst,r)-keyed runs: per run
// accumulate into ONE register, flush once per non-empty run.

__global__ __launch_bounds__(256) void k_aggregate6(
    const float* __restrict__ vbuf, const float* __restrict__ a_ws,
    const int* __restrict__ beg6, const int* __restrict__ esrc_s,
    const float* __restrict__ rel_msg,
    float* __restrict__ hacc, int n, int nE) {
    __shared__ float wsum[2][R_TYPES * 128];   // 6 KB
    __shared__ int bounds[2][R_TYPES + 1];
    int tid = threadIdx.x;
    int nb = tid >> 7;
    int lane2 = tid & 127;
    int node = blockIdx.x * 2 + nb;
    bool valid = node < n;
    int h = lane2 >> 4;
    int d = lane2 & 15;
    if (lane2 <= R_TYPES) {
        int idx = node * R_TYPES + lane2;
        bounds[nb][lane2] = valid ? ((idx < n * R_TYPES) ? beg6[idx] : nE) : 0;
    }
    __syncthreads();

    float* wsn = &wsum[nb][0];
#pragma unroll
    for (int rr = 0; rr < R_TYPES; ++rr) wsn[rr * 128 + lane2] = 0.f;

    float den = 0.f;
#pragma unroll
    for (int rr = 0; rr < R_TYPES; ++rr) {
        int b0 = bounds[nb][rr], b1 = bounds[nb][rr + 1];
        if (b0 == b1) continue;                  // wave-uniform branch
        float racc = 0.f;
        for (int p = b0; p < b1; ++p) {
            float av = a_ws[(size_t)p * 8 + h];  // broadcast within h-group
            float ex = __expf(av - SM_SHIFT);
            den += ex;
            int s = esrc_s[p];                   // wave-broadcast load
            racc = fmaf(ex, vbuf[(size_t)s * DIM + lane2], racc);
        }
        wsn[rr * 128 + lane2] = racc;
    }
    __syncthreads();

    // epilogue: out[h][d] = (1/den) * sum_r sum_dp bucket[r][h][dp] * M[h][r][dp][d]
    float acc = 0.f;
#pragma unroll
    for (int rr = 0; rr < R_TYPES; ++rr) {
        const float*  M   = rel_msg + ((size_t)h * R_TYPES + rr) * 256;
        const float4* blr = (const float4*)&wsn[rr * 128 + h * 16];
#pragma unroll
        for (int dq = 0; dq < 4; ++dq) {
            float4 bv = blr[dq];
            acc = fmaf(bv.x, M[(dq * 4 + 0) * 16 + d], acc);
            acc = fmaf(bv.y, M[(dq * 4 + 1) * 16 + d], acc);
            acc = fmaf(bv.z, M[(dq * 4 + 2) * 16 + d], acc);
            acc = fmaf(bv.w, M[(dq * 4 + 3) * 16 + d], acc);
        }
    }
    if (valid)
        hacc[(size_t)node * DIM + lane2] = acc / fmaxf(den, 1e-9f);
}

// ======================= K4: tiled Wa + gate + residual + LayerNorm ===========

__global__ __launch_bounds__(256) void k_final_gemm(
    const float* __restrict__ x, const int* __restrict__ nlist,
    const int* __restrict__ tile_type, const int* __restrict__ ntiles_g,
    const float* __restrict__ Wa, const float* __restrict__ skip,
    const float* __restrict__ gamma, const float* __restrict__ beta,
    float* __restrict__ out) {
    __shared__ float hs[BN][DIM];
    __shared__ float ys[BN][DIM];
    __shared__ int sids[BN];
    __shared__ float mred[BN], ired[BN];
    int b = blockIdx.x;
    if (b >= *ntiles_g) return;
    int tid = threadIdx.x;
    if (tid < BN) sids[tid] = nlist[b * BN + tid];
    __syncthreads();
    for (int idx = tid; idx < BN * DIM; idx += 256) {
        int row = idx >> 7, col = idx & 127;
        int nid = sids[row];
        hs[row][col] = (nid >= 0) ? out[(size_t)nid * DIM + col] : 0.f;
    }
    __syncthreads();
    int t = tile_type[b];
    int half = tid >> 7, col = tid & 127;
    const float* W = Wa + (size_t)t * DIM * DIM;
    float acc[8];
#pragma unroll
    for (int n = 0; n < 8; ++n) acc[n] = 0.f;
#pragma unroll 4
    for (int d = 0; d < DIM; ++d) {
        float w = W[d * DIM + col];
#pragma unroll
        for (int n = 0; n < 8; ++n) acc[n] = fmaf(hs[half * 8 + n][d], w, acc[n]);
    }
    float gte = 1.f / (1.f + __expf(-skip[t]));
#pragma unroll
    for (int n = 0; n < 8; ++n) {
        int row = half * 8 + n;
        int nid = sids[row];
        float xv = (nid >= 0) ? x[(size_t)nid * DIM + col] : 0.f;
        ys[row][col] = xv * (2.f - gte) + acc[n] * gte;
    }
    __syncthreads();
    int ng = tid >> 4, l16 = tid & 15;
    float s = 0.f, s2 = 0.f;
#pragma unroll
    for (int k2 = 0; k2 < 8; ++k2) {
        float yv = ys[ng][l16 + 16 * k2];
        s += yv; s2 += yv * yv;
    }
#pragma unroll
    for (int m = 1; m < 16; m <<= 1) {
        s  += __shfl_xor(s, m, 64);
        s2 += __shfl_xor(s2, m, 64);
    }
    if (l16 == 0) {
        float mu = s * (1.f / DIM);
        float var = s2 * (1.f / DIM) - mu * mu;
        mred[ng] = mu;
        ired[ng] = rsqrtf(var + 1e-5f);
    }
    __syncthreads();
    float gm = gamma[col], bt = beta[col];
#pragma unroll
    for (int n = 0; n < 8; ++n) {
        int row = half * 8 + n;
        int nid = sids[row];
        if (nid >= 0)
            out[(size_t)nid * DIM + col] = (ys[row][col] - mred[row]) * ired[row] * gm + bt;
    }
}

// ======================= launcher =======================

extern "C" void kernel_launch(void* const* d_in, const int* in_sizes, int n_in,
                              void* d_out, int out_size, void* d_ws, size_t ws_size,
                              hipStream_t stream) {
    const float* x       = (const float*)d_in[0];
    const int*   src     = (const int*)d_in[1];
    const int*   dst     = (const int*)d_in[2];
    const int*   ntype   = (const int*)d_in[3];
    const int*   etype   = (const int*)d_in[4];
    const float* Wk      = (const float*)d_in[5];
    const float* Wq      = (const float*)d_in[6];
    const float* Wv      = (const float*)d_in[7];
    const float* Wa      = (const float*)d_in[8];
    const float* rel_pri = (const float*)d_in[9];
    const float* rel_att = (const float*)d_in[10];
    const float* rel_msg = (const float*)d_in[11];
    const float* skip    = (const float*)d_in[12];
    const float* gamma   = (const float*)d_in[13];
    const float* beta    = (const float*)d_in[14];
    float* out = (float*)d_out;

    const int N = N_NODES, E = N_EDGES;

    // workspace layout
    char* ws = (char*)d_ws;
    float* kb   = (float*)ws;                          // N*128
    float* qb   = kb + (size_t)N * DIM;                // N*128
    float* vb   = qb + (size_t)N * DIM;                // N*128
    float* a_ws = vb + (size_t)N * DIM;                // E*8
    int* deg6    = (int*)(a_ws + (size_t)E * H_HEADS); // NKEYS
    int* beg6    = deg6 + NKEYS;                       // NKEYS
    int* cursor6 = beg6 + NKEYS;                       // NKEYS
    int* partial6 = cursor6 + NKEYS;                   // NBLK_K
    int* esrc_s  = partial6 + NBLK_K;                  // E
    int* edst_s  = esrc_s + E;                         // E
    int* ety_s   = edst_s + E;                         // E
    int* sp_src  = ety_s + E;                          // E
    int* sp_dst  = sp_src + E;                         // E
    int* sp_r    = sp_dst + E;                         // E
    int* sp_pos  = sp_r + E;                           // E
    int* rhist   = sp_pos + E;                         // R_TYPES*NBLK_E
    int* tcnt    = rhist + R_TYPES * NBLK_E;           // 4
    int* pbase   = tcnt + T_TYPES;                     // 4
    int* ntiles  = pbase + T_TYPES;                    // 1
    int* tile_type = ntiles + 1;                       // MAX_TILES
    int* nlist   = tile_type + MAX_TILES;              // MAX_TILES*BN
    int* wpos    = nlist + (size_t)MAX_TILES * BN;     // N

    const int nbScan = (N + 255) / 256;

    // (dst,r)-keyed CSR build
    hipMemsetAsync(deg6, 0, (size_t)NKEYS * sizeof(int), stream);
    k_count6<<<(E + 255) / 256, 256, 0, stream>>>(dst, etype, deg6, E);
    k_scanA<<<NBLK_K, 256, 0, stream>>>(deg6, beg6, partial6, NKEYS);
    k_rscan<<<1, 256, 0, stream>>>(partial6, NBLK_K);
    k_scanC<<<NBLK_K, 256, 0, stream>>>(beg6, partial6, NKEYS);
    hipMemcpyAsync(cursor6, beg6, (size_t)NKEYS * sizeof(int),
                   hipMemcpyDeviceToDevice, stream);
    k_scatter6<<<(E + 255) / 256, 256, 0, stream>>>(
        src, dst, etype, cursor6, esrc_s, edst_s, ety_s, E);

    // global counting-sort of CSR positions by relation type (for k_edge_a2)
    k_rhist<<<NBLK_E, 256, 0, stream>>>(ety_s, rhist, E);
    k_rscan<<<1, 256, 0, stream>>>(rhist, R_TYPES * NBLK_E);
    k_rscatter<<<NBLK_E, 256, 0, stream>>>(
        esrc_s, edst_s, ety_s, rhist, sp_src, sp_dst, sp_r, sp_pos, E);

    // node type buckets (padded 16-node tiles)
    hipMemsetAsync(tcnt, 0, T_TYPES * sizeof(int), stream);
    k_tcount_agg<<<nbScan, 256, 0, stream>>>(ntype, tcnt, wpos, N);
    k_tsetup<<<1, 256, 0, stream>>>(tcnt, pbase, ntiles, tile_type);
    hipMemsetAsync(nlist, 0xFF, (size_t)MAX_TILES * BN * sizeof(int), stream);
    k_tscatter2<<<nbScan, 256, 0, stream>>>(ntype, wpos, pbase, nlist, N);

    // projections (tiled per-type GEMM, 1 tile/block, 192 threads, full-chip grid)
    k_kqv_gemm3<<<MAX_TILES, 192, 0, stream>>>(
        x, nlist, tile_type, ntiles, Wk, Wq, Wv, kb, qb, vb);

    // edge logits (r-sorted, conflict-free LDS)
    k_edge_a2<<<(E + 31) / 32, 256, 0, stream>>>(
        kb, qb, sp_src, sp_dst, sp_r, sp_pos, rel_att, rel_pri, a_ws, E);

    // per-node softmax + message aggregation -> d_out (scratch)
    k_aggregate6<<<(N + 1) / 2, 256, 0, stream>>>(
        vb, a_ws, beg6, esrc_s, rel_msg, out, N, E);

    // output projection + gate + residual + LayerNorm (in place on d_out)
    k_final_gemm<<<MAX_TILES, 256, 0, stream>>>(
        x, nlist, tile_type, ntiles, Wa, skip, gamma, beta, out);
}

// Round 9
// 406.281 us; speedup vs baseline: 1.3423x; 1.1158x over previous
//
#include <hip/hip_runtime.h>
#include <math.h>

#define N_NODES 50000
#define N_EDGES 400000
#define H_HEADS 8
#define D_HEAD 16
#define R_TYPES 6
#define T_TYPES 4
#define DIM 128
#define BN 16                                      // nodes per GEMM tile
#define MAX_TILES ((N_NODES + BN - 1) / BN + T_TYPES)
#define NKEYS (N_NODES * R_TYPES)                  // 300000 (r,dst) buckets, r-major
#define NBLK_K ((NKEYS + 255) / 256)               // 1172
#define SM_SHIFT 8.0f                              // constant softmax shift

// ======================= generic scan pieces =======================

__global__ void k_scanA(const int* __restrict__ cnt, int* __restrict__ offs,
                        int* __restrict__ partial, int n) {
    __shared__ int tmp[256];
    int tid = threadIdx.x;
    int i = blockIdx.x * 256 + tid;
    int v = (i < n) ? cnt[i] : 0;
    tmp[tid] = v;
    __syncthreads();
    for (int o = 1; o < 256; o <<= 1) {
        int t = (tid >= o) ? tmp[tid - o] : 0;
        __syncthreads();
        tmp[tid] += t;
        __syncthreads();
    }
    if (i < n) offs[i] = tmp[tid] - v;           // exclusive within block
    if (tid == 255) partial[blockIdx.x] = tmp[255];
}

// single-block chunked exclusive scan (arbitrary length)
__global__ void k_rscan(int* __restrict__ a, int total) {
    __shared__ int tmp[256];
    __shared__ int carry_s;
    int tid = threadIdx.x;
    if (tid == 0) carry_s = 0;
    __syncthreads();
    for (int base = 0; base < total; base += 256) {
        int i = base + tid;
        int v = (i < total) ? a[i] : 0;
        tmp[tid] = v;
        __syncthreads();
        for (int o = 1; o < 256; o <<= 1) {
            int t = (tid >= o) ? tmp[tid - o] : 0;
            __syncthreads();
            tmp[tid] += t;
            __syncthreads();
        }
        int carry = carry_s;
        if (i < total) a[i] = carry + tmp[tid] - v;   // exclusive
        __syncthreads();
        if (tid == 255) carry_s = carry + tmp[255];
        __syncthreads();
    }
}

__global__ void k_scanC(int* __restrict__ offs, const int* __restrict__ partial, int n) {
    int i = blockIdx.x * 256 + threadIdx.x;
    if (i < n) offs[i] += partial[blockIdx.x];
}

// ======================= r-major (r,dst)-keyed CSR build =======================
// key = etype*N + dst  ->  edge list globally r-sorted AND dst-sorted within r;
// each (node,r) run contiguous. One sort serves both edge_a and aggregate.

__global__ void k_count6(const int* __restrict__ dst, const int* __restrict__ etype,
                         int* __restrict__ deg6, int n) {
    int e = blockIdx.x * blockDim.x + threadIdx.x;
    if (e < n) atomicAdd(&deg6[etype[e] * N_NODES + dst[e]], 1);
}

__global__ void k_scatter6(const int* __restrict__ src, const int* __restrict__ dst,
                           const int* __restrict__ etype, int* __restrict__ cursor6,
                           int* __restrict__ esrc_s, int* __restrict__ edst_s, int n) {
    int e = blockIdx.x * blockDim.x + threadIdx.x;
    if (e < n) {
        int key = etype[e] * N_NODES + dst[e];
        int pos = atomicAdd(&cursor6[key], 1);
        esrc_s[pos] = src[e];
        edst_s[pos] = dst[e];
    }
}

// ======================= node type bucketing (padded 16-node tiles) ===========

__global__ void k_tcount_agg(const int* __restrict__ ntype, int* __restrict__ tcnt,
                             int* __restrict__ wpos, int n) {
    __shared__ int hist[T_TYPES];
    __shared__ int base[T_TYPES];
    int tid = threadIdx.x;
    if (tid < T_TYPES) hist[tid] = 0;
    __syncthreads();
    int i = blockIdx.x * 256 + tid;
    int t = 0, rank = 0;
    if (i < n) {
        t = ntype[i];
        rank = atomicAdd(&hist[t], 1);
    }
    __syncthreads();
    if (tid < T_TYPES)
        base[tid] = (hist[tid] > 0) ? atomicAdd(&tcnt[tid], hist[tid]) : 0;
    __syncthreads();
    if (i < n) wpos[i] = base[t] + rank;
}

__global__ void k_tsetup(const int* __restrict__ tcnt, int* __restrict__ pbase,
                         int* __restrict__ ntiles_g, int* __restrict__ tile_type) {
    __shared__ int off[T_TYPES + 1];
    if (threadIdx.x == 0) {
        int o = 0;
        for (int t = 0; t < T_TYPES; ++t) {
            off[t] = o;
            pbase[t] = o * BN;
            o += (tcnt[t] + BN - 1) / BN;
        }
        off[T_TYPES] = o;
        *ntiles_g = o;
    }
    __syncthreads();
    int total = off[T_TYPES];
    for (int i = threadIdx.x; i < total; i += blockDim.x) {
        int t = 0;
        while (t < T_TYPES - 1 && i >= off[t + 1]) ++t;
        tile_type[i] = t;
    }
}

__global__ void k_tscatter2(const int* __restrict__ ntype, const int* __restrict__ wpos,
                            const int* __restrict__ pbase, int* __restrict__ nlist, int n) {
    int i = blockIdx.x * 256 + threadIdx.x;
    if (i < n) nlist[pbase[ntype[i]] + wpos[i]] = i;
}

// ======================= K1: tiled typed-linear k,q,v (v3) =======================
// One 16-node tile per block, 192 threads = 2 node-halves x 3 mats x 32 col-quads.

__global__ __launch_bounds__(192) void k_kqv_gemm3(
    const float* __restrict__ x, const int* __restrict__ nlist,
    const int* __restrict__ tile_type, const int* __restrict__ ntiles_g,
    const float* __restrict__ Wk, const float* __restrict__ Wq,
    const float* __restrict__ Wv,
    float* __restrict__ kb, float* __restrict__ qb, float* __restrict__ vb) {
    __shared__ float xs[BN][DIM];   // 8 KB
    __shared__ int sids[BN];
    int b = blockIdx.x;
    if (b >= *ntiles_g) return;
    int tid = threadIdx.x;
    if (tid < BN) sids[tid] = nlist[b * BN + tid];
    __syncthreads();
    for (int idx = tid; idx < BN * (DIM / 4); idx += 192) {
        int row = idx >> 5;
        int q4 = idx & 31;
        int nid = sids[row];
        float4 v4 = make_float4(0.f, 0.f, 0.f, 0.f);
        if (nid >= 0) v4 = *(const float4*)(x + (size_t)nid * DIM + q4 * 4);
        *(float4*)(&xs[row][q4 * 4]) = v4;
    }
    __syncthreads();
    int lt = tid / 96;            // node half: rows lt*8 .. lt*8+7
    int wi = tid % 96;
    int mat = wi >> 5;            // 0=k 1=q 2=v
    int colq = wi & 31;
    int t = tile_type[b];
    const float* W = (mat == 0 ? Wk : (mat == 1 ? Wq : Wv))
                     + (size_t)t * DIM * DIM + colq * 4;
    float acc[8][4];
#pragma unroll
    for (int n = 0; n < 8; ++n) {
        acc[n][0] = 0.f; acc[n][1] = 0.f; acc[n][2] = 0.f; acc[n][3] = 0.f;
    }
    const float* xbase = &xs[lt * 8][0];
    for (int dq = 0; dq < 32; ++dq) {
        float4 w0 = *(const float4*)(W + (size_t)(dq * 4 + 0) * DIM);
        float4 w1 = *(const float4*)(W + (size_t)(dq * 4 + 1) * DIM);
        float4 w2 = *(const float4*)(W + (size_t)(dq * 4 + 2) * DIM);
        float4 w3 = *(const float4*)(W + (size_t)(dq * 4 + 3) * DIM);
#pragma unroll
        for (int n = 0; n < 8; ++n) {
            float4 xv = *(const float4*)(xbase + n * DIM + dq * 4);
            acc[n][0] = fmaf(xv.x, w0.x, acc[n][0]);
            acc[n][0] = fmaf(xv.y, w1.x, acc[n][0]);
            acc[n][0] = fmaf(xv.z, w2.x, acc[n][0]);
            acc[n][0] = fmaf(xv.w, w3.x, acc[n][0]);
            acc[n][1] = fmaf(xv.x, w0.y, acc[n][1]);
            acc[n][1] = fmaf(xv.y, w1.y, acc[n][1]);
            acc[n][1] = fmaf(xv.z, w2.y, acc[n][1]);
            acc[n][1] = fmaf(xv.w, w3.y, acc[n][1]);
            acc[n][2] = fmaf(xv.x, w0.z, acc[n][2]);
            acc[n][2] = fmaf(xv.y, w1.z, acc[n][2]);
            acc[n][2] = fmaf(xv.z, w2.z, acc[n][2]);
            acc[n][2] = fmaf(xv.w, w3.z, acc[n][2]);
            acc[n][3] = fmaf(xv.x, w0.w, acc[n][3]);
            acc[n][3] = fmaf(xv.y, w1.w, acc[n][3]);
            acc[n][3] = fmaf(xv.z, w2.w, acc[n][3]);
            acc[n][3] = fmaf(xv.w, w3.w, acc[n][3]);
        }
    }
    float* ob = (mat == 0 ? kb : (mat == 1 ? qb : vb));
#pragma unroll
    for (int n = 0; n < 8; ++n) {
        int nid = sids[lt * 8 + n];
        if (nid >= 0)
            *(float4*)(ob + (size_t)nid * DIM + colq * 4) =
                make_float4(acc[n][0], acc[n][1], acc[n][2], acc[n][3]);
    }
}

// ======================= K2: per-edge attention logits (v3) =============
// Edge list is globally r-sorted (r-major CSR): r per entry derived from the 6
// global boundaries rb[] -- no sp_* arrays, a_ws written coalesced in place.

__global__ __launch_bounds__(256) void k_edge_a3(
    const float* __restrict__ kbuf, const float* __restrict__ qbuf,
    const int* __restrict__ esrc_s, const int* __restrict__ edst_s,
    const int* __restrict__ beg6,
    const float* __restrict__ rel_att, const float* __restrict__ rel_pri,
    float* __restrict__ a_ws, int nE) {
    __shared__ float A2[2][8 * 260];   // 2 r-slots, 8 heads, 16x16 each (stride 260)
    __shared__ float pri[2][8];
    __shared__ int rb_s[R_TYPES + 1];
    __shared__ int r01[2];
    int b = blockIdx.x;
    int e0 = b * 32;
    int tid = threadIdx.x;
    int nHere = nE - e0; if (nHere > 32) nHere = 32;
    if (nHere <= 0) return;
    if (tid < R_TYPES) rb_s[tid] = beg6[tid * N_NODES];   // start of relation r
    if (tid == R_TYPES) rb_s[R_TYPES] = nE;
    __syncthreads();
    if (tid == 0) {
        int rA = 0, rB = 0;
        int eL = e0 + nHere - 1;
#pragma unroll
        for (int r = 1; r < R_TYPES; ++r) {
            if (e0 >= rb_s[r]) rA = r;
            if (eL >= rb_s[r]) rB = r;
        }
        r01[0] = rA; r01[1] = rB;
    }
    __syncthreads();
    int r0 = r01[0], r1 = r01[1];
    int bnd = rb_s[r0 + 1];                   // entries >= bnd belong to r1
    for (int idx = tid; idx < 2 * 2048; idx += 256) {
        int slot = idx >> 11;
        if (slot == 1 && r1 == r0) break;
        int rem = idx & 2047;
        int h = rem >> 8, dj = rem & 255;
        int rr = slot ? r1 : r0;
        A2[slot][h * 260 + dj] = rel_att[(h * R_TYPES + rr) * 256 + dj];
    }
    if (tid < 16) {
        int slot = tid >> 3, h = tid & 7;
        pri[slot][h] = rel_pri[h * R_TYPES + (slot ? r1 : r0)] * 0.25f;
    }
    __syncthreads();
    int el = tid >> 3;
    int h  = tid & 7;
    int q2 = e0 + el;
    if (q2 >= nE) return;
    int s = esrc_s[q2], dn = edst_s[q2];
    int slot = (q2 >= bnd) ? 1 : 0;
    const float4* kp = (const float4*)(kbuf + (size_t)s  * DIM + h * 16);
    const float4* qp = (const float4*)(qbuf + (size_t)dn * DIM + h * 16);
    float4 k4[4], q4[4];
#pragma unroll
    for (int i = 0; i < 4; ++i) { k4[i] = kp[i]; q4[i] = qp[i]; }
    float kk[16] = {k4[0].x,k4[0].y,k4[0].z,k4[0].w, k4[1].x,k4[1].y,k4[1].z,k4[1].w,
                    k4[2].x,k4[2].y,k4[2].z,k4[2].w, k4[3].x,k4[3].y,k4[3].z,k4[3].w};
    float qq[16] = {q4[0].x,q4[0].y,q4[0].z,q4[0].w, q4[1].x,q4[1].y,q4[1].z,q4[1].w,
                    q4[2].x,q4[2].y,q4[2].z,q4[2].w, q4[3].x,q4[3].y,q4[3].z,q4[3].w};
    const float4* A4 = (const float4*)&A2[slot][h * 260];
    float accj[16];
#pragma unroll
    for (int j = 0; j < 16; ++j) accj[j] = 0.f;
#pragma unroll
    for (int d = 0; d < 16; ++d) {
        float kd = kk[d];
#pragma unroll
        for (int jj = 0; jj < 4; ++jj) {
            float4 a4 = A4[d * 4 + jj];
            accj[jj * 4 + 0] = fmaf(kd, a4.x, accj[jj * 4 + 0]);
            accj[jj * 4 + 1] = fmaf(kd, a4.y, accj[jj * 4 + 1]);
            accj[jj * 4 + 2] = fmaf(kd, a4.z, accj[jj * 4 + 2]);
            accj[jj * 4 + 3] = fmaf(kd, a4.w, accj[jj * 4 + 3]);
        }
    }
    float acc = 0.f;
#pragma unroll
    for (int j = 0; j < 16; ++j) acc = fmaf(accj[j], qq[j], acc);
    a_ws[(size_t)q2 * 8 + h] = acc * pri[slot][h];   // coalesced (own position)
}

// ======================= K3: per-node softmax + aggregation (v7) ==============
// 128 threads/node, 2 nodes/block. r-major CSR: run (r,node) = [beg6[r*N+node],
// beg6[key+1]) -- exclusive scan is continuous so end works across r boundaries.
// Constant-shift softmax (no max pass). Per run: single-register accumulate.

__global__ __launch_bounds__(256) void k_aggregate7(
    const float* __restrict__ vbuf, const float* __restrict__ a_ws,
    const int* __restrict__ beg6, const int* __restrict__ esrc_s,
    const float* __restrict__ rel_msg,
    float* __restrict__ hacc, int n, int nE) {
    __shared__ float wsum[2][R_TYPES * 128];   // 6 KB
    __shared__ int bb[2][2 * R_TYPES];         // beg[r], end[r] per node
    int tid = threadIdx.x;
    int nb = tid >> 7;
    int lane2 = tid & 127;
    int node = blockIdx.x * 2 + nb;
    bool valid = node < n;
    int h = lane2 >> 4;
    int d = lane2 & 15;
    if (lane2 < 2 * R_TYPES) {
        int rr = lane2 >= R_TYPES ? lane2 - R_TYPES : lane2;
        int key = rr * N_NODES + (valid ? node : 0);
        int val;
        if (lane2 < R_TYPES) val = valid ? beg6[key] : 0;
        else                 val = valid ? ((key + 1 < NKEYS) ? beg6[key + 1] : nE) : 0;
        bb[nb][lane2] = val;
    }
    __syncthreads();

    float* wsn = &wsum[nb][0];
#pragma unroll
    for (int rr = 0; rr < R_TYPES; ++rr) wsn[rr * 128 + lane2] = 0.f;

    float den = 0.f;
#pragma unroll
    for (int rr = 0; rr < R_TYPES; ++rr) {
        int b0 = bb[nb][rr], b1 = bb[nb][R_TYPES + rr];
        if (b0 == b1) continue;                  // wave-uniform branch
        float racc = 0.f;
        for (int p = b0; p < b1; ++p) {
            float av = a_ws[(size_t)p * 8 + h];  // broadcast within h-group
            float ex = __expf(av - SM_SHIFT);
            den += ex;
            int s = esrc_s[p];                   // wave-broadcast load
            racc = fmaf(ex, vbuf[(size_t)s * DIM + lane2], racc);
        }
        wsn[rr * 128 + lane2] = racc;
    }
    __syncthreads();

    // epilogue: out[h][d] = (1/den) * sum_r sum_dp bucket[r][h][dp] * M[h][r][dp][d]
    float acc = 0.f;
#pragma unroll
    for (int rr = 0; rr < R_TYPES; ++rr) {
        const float*  M   = rel_msg + ((size_t)h * R_TYPES + rr) * 256;
        const float4* blr = (const float4*)&wsn[rr * 128 + h * 16];
#pragma unroll
        for (int dq = 0; dq < 4; ++dq) {
            float4 bv = blr[dq];
            acc = fmaf(bv.x, M[(dq * 4 + 0) * 16 + d], acc);
            acc = fmaf(bv.y, M[(dq * 4 + 1) * 16 + d], acc);
            acc = fmaf(bv.z, M[(dq * 4 + 2) * 16 + d], acc);
            acc = fmaf(bv.w, M[(dq * 4 + 3) * 16 + d], acc);
        }
    }
    if (valid)
        hacc[(size_t)node * DIM + lane2] = acc / fmaxf(den, 1e-9f);
}

// ======================= K4: tiled Wa + gate + residual + LayerNorm ===========

__global__ __launch_bounds__(256) void k_final_gemm(
    const float* __restrict__ x, const int* __restrict__ nlist,
    const int* __restrict__ tile_type, const int* __restrict__ ntiles_g,
    const float* __restrict__ Wa, const float* __restrict__ skip,
    const float* __restrict__ gamma, const float* __restrict__ beta,
    float* __restrict__ out) {
    __shared__ float hs[BN][DIM];
    __shared__ float ys[BN][DIM];
    __shared__ int sids[BN];
    __shared__ float mred[BN], ired[BN];
    int b = blockIdx.x;
    if (b >= *ntiles_g) return;
    int tid = threadIdx.x;
    if (tid < BN) sids[tid] = nlist[b * BN + tid];
    __syncthreads();
    for (int idx = tid; idx < BN * DIM; idx += 256) {
        int row = idx >> 7, col = idx & 127;
        int nid = sids[row];
        hs[row][col] = (nid >= 0) ? out[(size_t)nid * DIM + col] : 0.f;
    }
    __syncthreads();
    int t = tile_type[b];
    int half = tid >> 7, col = tid & 127;
    const float* W = Wa + (size_t)t * DIM * DIM;
    float acc[8];
#pragma unroll
    for (int n = 0; n < 8; ++n) acc[n] = 0.f;
#pragma unroll 4
    for (int d = 0; d < DIM; ++d) {
        float w = W[d * DIM + col];
#pragma unroll
        for (int n = 0; n < 8; ++n) acc[n] = fmaf(hs[half * 8 + n][d], w, acc[n]);
    }
    float gte = 1.f / (1.f + __expf(-skip[t]));
#pragma unroll
    for (int n = 0; n < 8; ++n) {
        int row = half * 8 + n;
        int nid = sids[row];
        float xv = (nid >= 0) ? x[(size_t)nid * DIM + col] : 0.f;
        ys[row][col] = xv * (2.f - gte) + acc[n] * gte;
    }
    __syncthreads();
    int ng = tid >> 4, l16 = tid & 15;
    float s = 0.f, s2 = 0.f;
#pragma unroll
    for (int k2 = 0; k2 < 8; ++k2) {
        float yv = ys[ng][l16 + 16 * k2];
        s += yv; s2 += yv * yv;
    }
#pragma unroll
    for (int m = 1; m < 16; m <<= 1) {
        s  += __shfl_xor(s, m, 64);
        s2 += __shfl_xor(s2, m, 64);
    }
    if (l16 == 0) {
        float mu = s * (1.f / DIM);
        float var = s2 * (1.f / DIM) - mu * mu;
        mred[ng] = mu;
        ired[ng] = rsqrtf(var + 1e-5f);
    }
    __syncthreads();
    float gm = gamma[col], bt = beta[col];
#pragma unroll
    for (int n = 0; n < 8; ++n) {
        int row = half * 8 + n;
        int nid = sids[row];
        if (nid >= 0)
            out[(size_t)nid * DIM + col] = (ys[row][col] - mred[row]) * ired[row] * gm + bt;
    }
}

// ======================= launcher =======================

extern "C" void kernel_launch(void* const* d_in, const int* in_sizes, int n_in,
                              void* d_out, int out_size, void* d_ws, size_t ws_size,
                              hipStream_t stream) {
    const float* x       = (const float*)d_in[0];
    const int*   src     = (const int*)d_in[1];
    const int*   dst     = (const int*)d_in[2];
    const int*   ntype   = (const int*)d_in[3];
    const int*   etype   = (const int*)d_in[4];
    const float* Wk      = (const float*)d_in[5];
    const float* Wq      = (const float*)d_in[6];
    const float* Wv      = (const float*)d_in[7];
    const float* Wa      = (const float*)d_in[8];
    const float* rel_pri = (const float*)d_in[9];
    const float* rel_att = (const float*)d_in[10];
    const float* rel_msg = (const float*)d_in[11];
    const float* skip    = (const float*)d_in[12];
    const float* gamma   = (const float*)d_in[13];
    const float* beta    = (const float*)d_in[14];
    float* out = (float*)d_out;

    const int N = N_NODES, E = N_EDGES;

    // workspace layout
    char* ws = (char*)d_ws;
    float* kb   = (float*)ws;                          // N*128
    float* qb   = kb + (size_t)N * DIM;                // N*128
    float* vb   = qb + (size_t)N * DIM;                // N*128
    float* a_ws = vb + (size_t)N * DIM;                // E*8
    int* deg6    = (int*)(a_ws + (size_t)E * H_HEADS); // NKEYS
    int* beg6    = deg6 + NKEYS;                       // NKEYS
    int* cursor6 = beg6 + NKEYS;                       // NKEYS
    int* partial6 = cursor6 + NKEYS;                   // NBLK_K
    int* esrc_s  = partial6 + NBLK_K;                  // E
    int* edst_s  = esrc_s + E;                         // E
    int* tcnt    = edst_s + E;                         // 4
    int* pbase   = tcnt + T_TYPES;                     // 4
    int* ntiles  = pbase + T_TYPES;                    // 1
    int* tile_type = ntiles + 1;                       // MAX_TILES
    int* nlist   = tile_type + MAX_TILES;              // MAX_TILES*BN
    int* wpos    = nlist + (size_t)MAX_TILES * BN;     // N

    const int nbScan = (N + 255) / 256;

    // r-major (r,dst)-keyed CSR build (single sort serves edge_a AND aggregate)
    hipMemsetAsync(deg6, 0, (size_t)NKEYS * sizeof(int), stream);
    k_count6<<<(E + 255) / 256, 256, 0, stream>>>(dst, etype, deg6, E);
    k_scanA<<<NBLK_K, 256, 0, stream>>>(deg6, beg6, partial6, NKEYS);
    k_rscan<<<1, 256, 0, stream>>>(partial6, NBLK_K);
    k_scanC<<<NBLK_K, 256, 0, stream>>>(beg6, partial6, NKEYS);
    hipMemcpyAsync(cursor6, beg6, (size_t)NKEYS * sizeof(int),
                   hipMemcpyDeviceToDevice, stream);
    k_scatter6<<<(E + 255) / 256, 256, 0, stream>>>(
        src, dst, etype, cursor6, esrc_s, edst_s, E);

    // node type buckets (padded 16-node tiles)
    hipMemsetAsync(tcnt, 0, T_TYPES * sizeof(int), stream);
    k_tcount_agg<<<nbScan, 256, 0, stream>>>(ntype, tcnt, wpos, N);
    k_tsetup<<<1, 256, 0, stream>>>(tcnt, pbase, ntiles, tile_type);
    hipMemsetAsync(nlist, 0xFF, (size_t)MAX_TILES * BN * sizeof(int), stream);
    k_tscatter2<<<nbScan, 256, 0, stream>>>(ntype, wpos, pbase, nlist, N);

    // projections (tiled per-type GEMM, full-chip grid)
    k_kqv_gemm3<<<MAX_TILES, 192, 0, stream>>>(
        x, nlist, tile_type, ntiles, Wk, Wq, Wv, kb, qb, vb);

    // edge logits (r-sorted by construction, coalesced a_ws write)
    k_edge_a3<<<(E + 31) / 32, 256, 0, stream>>>(
        kb, qb, esrc_s, edst_s, beg6, rel_att, rel_pri, a_ws, E);

    // per-node softmax + message aggregation -> d_out (scratch)
    k_aggregate7<<<(N + 1) / 2, 256, 0, stream>>>(
        vb, a_ws, beg6, esrc_s, rel_msg, out, N, E);

    // output projection + gate + residual + LayerNorm (in place on d_out)
    k_final_gemm<<<MAX_TILES, 256, 0, stream>>>(
        x, nlist, tile_type, ntiles, Wa, skip, gamma, beta, out);
}

// Round 10
// 402.612 us; speedup vs baseline: 1.3546x; 1.0091x over previous
//
#include <hip/hip_runtime.h>
#include <math.h>

#define N_NODES 50000
#define N_EDGES 400000
#define H_HEADS 8
#define D_HEAD 16
#define R_TYPES 6
#define T_TYPES 4
#define DIM 128
#define BN 16                                      // nodes per GEMM tile
#define MAX_TILES ((N_NODES + BN - 1) / BN + T_TYPES)
#define NKEYS (N_NODES * R_TYPES)                  // 300000 (r,dst) buckets, r-major
#define NBLK_K ((NKEYS + 255) / 256)               // 1172
#define SM_SHIFT 8.0f                              // constant softmax shift
#define MAXB 16                                    // agg edge batch (per node)

// ======================= generic scan pieces =======================

__global__ void k_scanA(const int* __restrict__ cnt, int* __restrict__ offs,
                        int* __restrict__ partial, int n) {
    __shared__ int tmp[256];
    int tid = threadIdx.x;
    int i = blockIdx.x * 256 + tid;
    int v = (i < n) ? cnt[i] : 0;
    tmp[tid] = v;
    __syncthreads();
    for (int o = 1; o < 256; o <<= 1) {
        int t = (tid >= o) ? tmp[tid - o] : 0;
        __syncthreads();
        tmp[tid] += t;
        __syncthreads();
    }
    if (i < n) offs[i] = tmp[tid] - v;           // exclusive within block
    if (tid == 255) partial[blockIdx.x] = tmp[255];
}

// single-block chunked exclusive scan (arbitrary length)
__global__ void k_rscan(int* __restrict__ a, int total) {
    __shared__ int tmp[256];
    __shared__ int carry_s;
    int tid = threadIdx.x;
    if (tid == 0) carry_s = 0;
    __syncthreads();
    for (int base = 0; base < total; base += 256) {
        int i = base + tid;
        int v = (i < total) ? a[i] : 0;
        tmp[tid] = v;
        __syncthreads();
        for (int o = 1; o < 256; o <<= 1) {
            int t = (tid >= o) ? tmp[tid - o] : 0;
            __syncthreads();
            tmp[tid] += t;
            __syncthreads();
        }
        int carry = carry_s;
        if (i < total) a[i] = carry + tmp[tid] - v;   // exclusive
        __syncthreads();
        if (tid == 255) carry_s = carry + tmp[255];
        __syncthreads();
    }
}

// add block offsets AND mirror into the scatter cursor (saves a d2d memcpy)
__global__ void k_scanC2(int* __restrict__ offs, const int* __restrict__ partial,
                         int* __restrict__ cursor, int n) {
    int i = blockIdx.x * 256 + threadIdx.x;
    if (i < n) {
        int v = offs[i] + partial[blockIdx.x];
        offs[i] = v;
        cursor[i] = v;
    }
}

// ======================= r-major (r,dst)-keyed CSR build =======================
// key = etype*N + dst  ->  edge list globally r-sorted AND dst-sorted within r;
// each (node,r) run contiguous. One sort serves both edge_a and aggregate.

__global__ void k_count6(const int* __restrict__ dst, const int* __restrict__ etype,
                         int* __restrict__ deg6, int n) {
    int e = blockIdx.x * blockDim.x + threadIdx.x;
    if (e < n) atomicAdd(&deg6[etype[e] * N_NODES + dst[e]], 1);
}

__global__ void k_scatter6(const int* __restrict__ src, const int* __restrict__ dst,
                           const int* __restrict__ etype, int* __restrict__ cursor6,
                           int* __restrict__ esrc_s, int* __restrict__ edst_s, int n) {
    int e = blockIdx.x * blockDim.x + threadIdx.x;
    if (e < n) {
        int key = etype[e] * N_NODES + dst[e];
        int pos = atomicAdd(&cursor6[key], 1);
        esrc_s[pos] = src[e];
        edst_s[pos] = dst[e];
    }
}

// ======================= node type bucketing (padded 16-node tiles) ===========

__global__ void k_tcount_agg(const int* __restrict__ ntype, int* __restrict__ tcnt,
                             int* __restrict__ wpos, int n) {
    __shared__ int hist[T_TYPES];
    __shared__ int base[T_TYPES];
    int tid = threadIdx.x;
    if (tid < T_TYPES) hist[tid] = 0;
    __syncthreads();
    int i = blockIdx.x * 256 + tid;
    int t = 0, rank = 0;
    if (i < n) {
        t = ntype[i];
        rank = atomicAdd(&hist[t], 1);
    }
    __syncthreads();
    if (tid < T_TYPES)
        base[tid] = (hist[tid] > 0) ? atomicAdd(&tcnt[tid], hist[tid]) : 0;
    __syncthreads();
    if (i < n) wpos[i] = base[t] + rank;
}

__global__ void k_tsetup(const int* __restrict__ tcnt, int* __restrict__ pbase,
                         int* __restrict__ ntiles_g, int* __restrict__ tile_type) {
    __shared__ int off[T_TYPES + 1];
    if (threadIdx.x == 0) {
        int o = 0;
        for (int t = 0; t < T_TYPES; ++t) {
            off[t] = o;
            pbase[t] = o * BN;
            o += (tcnt[t] + BN - 1) / BN;
        }
        off[T_TYPES] = o;
        *ntiles_g = o;
    }
    __syncthreads();
    int total = off[T_TYPES];
    for (int i = threadIdx.x; i < total; i += blockDim.x) {
        int t = 0;
        while (t < T_TYPES - 1 && i >= off[t + 1]) ++t;
        tile_type[i] = t;
    }
}

__global__ void k_tscatter2(const int* __restrict__ ntype, const int* __restrict__ wpos,
                            const int* __restrict__ pbase, int* __restrict__ nlist, int n) {
    int i = blockIdx.x * 256 + threadIdx.x;
    if (i < n) nlist[pbase[ntype[i]] + wpos[i]] = i;
}

// ======================= K1: tiled typed-linear k,q,v (v3) =======================
// One 16-node tile per block, 192 threads = 2 node-halves x 3 mats x 32 col-quads.

__global__ __launch_bounds__(192) void k_kqv_gemm3(
    const float* __restrict__ x, const int* __restrict__ nlist,
    const int* __restrict__ tile_type, const int* __restrict__ ntiles_g,
    const float* __restrict__ Wk, const float* __restrict__ Wq,
    const float* __restrict__ Wv,
    float* __restrict__ kb, float* __restrict__ qb, float* __restrict__ vb) {
    __shared__ float xs[BN][DIM];   // 8 KB
    __shared__ int sids[BN];
    int b = blockIdx.x;
    if (b >= *ntiles_g) return;
    int tid = threadIdx.x;
    if (tid < BN) sids[tid] = nlist[b * BN + tid];
    __syncthreads();
    for (int idx = tid; idx < BN * (DIM / 4); idx += 192) {
        int row = idx >> 5;
        int q4 = idx & 31;
        int nid = sids[row];
        float4 v4 = make_float4(0.f, 0.f, 0.f, 0.f);
        if (nid >= 0) v4 = *(const float4*)(x + (size_t)nid * DIM + q4 * 4);
        *(float4*)(&xs[row][q4 * 4]) = v4;
    }
    __syncthreads();
    int lt = tid / 96;            // node half: rows lt*8 .. lt*8+7
    int wi = tid % 96;
    int mat = wi >> 5;            // 0=k 1=q 2=v
    int colq = wi & 31;
    int t = tile_type[b];
    const float* W = (mat == 0 ? Wk : (mat == 1 ? Wq : Wv))
                     + (size_t)t * DIM * DIM + colq * 4;
    float acc[8][4];
#pragma unroll
    for (int n = 0; n < 8; ++n) {
        acc[n][0] = 0.f; acc[n][1] = 0.f; acc[n][2] = 0.f; acc[n][3] = 0.f;
    }
    const float* xbase = &xs[lt * 8][0];
    for (int dq = 0; dq < 32; ++dq) {
        float4 w0 = *(const float4*)(W + (size_t)(dq * 4 + 0) * DIM);
        float4 w1 = *(const float4*)(W + (size_t)(dq * 4 + 1) * DIM);
        float4 w2 = *(const float4*)(W + (size_t)(dq * 4 + 2) * DIM);
        float4 w3 = *(const float4*)(W + (size_t)(dq * 4 + 3) * DIM);
#pragma unroll
        for (int n = 0; n < 8; ++n) {
            float4 xv = *(const float4*)(xbase + n * DIM + dq * 4);
            acc[n][0] = fmaf(xv.x, w0.x, acc[n][0]);
            acc[n][0] = fmaf(xv.y, w1.x, acc[n][0]);
            acc[n][0] = fmaf(xv.z, w2.x, acc[n][0]);
            acc[n][0] = fmaf(xv.w, w3.x, acc[n][0]);
            acc[n][1] = fmaf(xv.x, w0.y, acc[n][1]);
            acc[n][1] = fmaf(xv.y, w1.y, acc[n][1]);
            acc[n][1] = fmaf(xv.z, w2.y, acc[n][1]);
            acc[n][1] = fmaf(xv.w, w3.y, acc[n][1]);
            acc[n][2] = fmaf(xv.x, w0.z, acc[n][2]);
            acc[n][2] = fmaf(xv.y, w1.z, acc[n][2]);
            acc[n][2] = fmaf(xv.z, w2.z, acc[n][2]);
            acc[n][2] = fmaf(xv.w, w3.z, acc[n][2]);
            acc[n][3] = fmaf(xv.x, w0.w, acc[n][3]);
            acc[n][3] = fmaf(xv.y, w1.w, acc[n][3]);
            acc[n][3] = fmaf(xv.z, w2.w, acc[n][3]);
            acc[n][3] = fmaf(xv.w, w3.w, acc[n][3]);
        }
    }
    float* ob = (mat == 0 ? kb : (mat == 1 ? qb : vb));
#pragma unroll
    for (int n = 0; n < 8; ++n) {
        int nid = sids[lt * 8 + n];
        if (nid >= 0)
            *(float4*)(ob + (size_t)nid * DIM + colq * 4) =
                make_float4(acc[n][0], acc[n][1], acc[n][2], acc[n][3]);
    }
}

// ======================= K2: per-edge attention logits (v3) =============

__global__ __launch_bounds__(256) void k_edge_a3(
    const float* __restrict__ kbuf, const float* __restrict__ qbuf,
    const int* __restrict__ esrc_s, const int* __restrict__ edst_s,
    const int* __restrict__ beg6,
    const float* __restrict__ rel_att, const float* __restrict__ rel_pri,
    float* __restrict__ a_ws, int nE) {
    __shared__ float A2[2][8 * 260];   // 2 r-slots, 8 heads, 16x16 each (stride 260)
    __shared__ float pri[2][8];
    __shared__ int rb_s[R_TYPES + 1];
    __shared__ int r01[2];
    int b = blockIdx.x;
    int e0 = b * 32;
    int tid = threadIdx.x;
    int nHere = nE - e0; if (nHere > 32) nHere = 32;
    if (nHere <= 0) return;
    if (tid < R_TYPES) rb_s[tid] = beg6[tid * N_NODES];   // start of relation r
    if (tid == R_TYPES) rb_s[R_TYPES] = nE;
    __syncthreads();
    if (tid == 0) {
        int rA = 0, rB = 0;
        int eL = e0 + nHere - 1;
#pragma unroll
        for (int r = 1; r < R_TYPES; ++r) {
            if (e0 >= rb_s[r]) rA = r;
            if (eL >= rb_s[r]) rB = r;
        }
        r01[0] = rA; r01[1] = rB;
    }
    __syncthreads();
    int r0 = r01[0], r1 = r01[1];
    int bnd = rb_s[r0 + 1];                   // entries >= bnd belong to r1
    for (int idx = tid; idx < 2 * 2048; idx += 256) {
        int slot = idx >> 11;
        if (slot == 1 && r1 == r0) break;
        int rem = idx & 2047;
        int h = rem >> 8, dj = rem & 255;
        int rr = slot ? r1 : r0;
        A2[slot][h * 260 + dj] = rel_att[(h * R_TYPES + rr) * 256 + dj];
    }
    if (tid < 16) {
        int slot = tid >> 3, h = tid & 7;
        pri[slot][h] = rel_pri[h * R_TYPES + (slot ? r1 : r0)] * 0.25f;
    }
    __syncthreads();
    int el = tid >> 3;
    int h  = tid & 7;
    int q2 = e0 + el;
    if (q2 >= nE) return;
    int s = esrc_s[q2], dn = edst_s[q2];
    int slot = (q2 >= bnd) ? 1 : 0;
    const float4* kp = (const float4*)(kbuf + (size_t)s  * DIM + h * 16);
    const float4* qp = (const float4*)(qbuf + (size_t)dn * DIM + h * 16);
    float4 k4[4], q4[4];
#pragma unroll
    for (int i = 0; i < 4; ++i) { k4[i] = kp[i]; q4[i] = qp[i]; }
    float kk[16] = {k4[0].x,k4[0].y,k4[0].z,k4[0].w, k4[1].x,k4[1].y,k4[1].z,k4[1].w,
                    k4[2].x,k4[2].y,k4[2].z,k4[2].w, k4[3].x,k4[3].y,k4[3].z,k4[3].w};
    float qq[16] = {q4[0].x,q4[0].y,q4[0].z,q4[0].w, q4[1].x,q4[1].y,q4[1].z,q4[1].w,
                    q4[2].x,q4[2].y,q4[2].z,q4[2].w, q4[3].x,q4[3].y,q4[3].z,q4[3].w};
    const float4* A4 = (const float4*)&A2[slot][h * 260];
    float accj[16];
#pragma unroll
    for (int j = 0; j < 16; ++j) accj[j] = 0.f;
#pragma unroll
    for (int d = 0; d < 16; ++d) {
        float kd = kk[d];
#pragma unroll
        for (int jj = 0; jj < 4; ++jj) {
            float4 a4 = A4[d * 4 + jj];
            accj[jj * 4 + 0] = fmaf(kd, a4.x, accj[jj * 4 + 0]);
            accj[jj * 4 + 1] = fmaf(kd, a4.y, accj[jj * 4 + 1]);
            accj[jj * 4 + 2] = fmaf(kd, a4.z, accj[jj * 4 + 2]);
            accj[jj * 4 + 3] = fmaf(kd, a4.w, accj[jj * 4 + 3]);
        }
    }
    float acc = 0.f;
#pragma unroll
    for (int j = 0; j < 16; ++j) acc = fmaf(accj[j], qq[j], acc);
    a_ws[(size_t)q2 * 8 + h] = acc * pri[slot][h];   // coalesced (own position)
}

// ======================= K3: per-node softmax + aggregation (v8) ==============
// 128 thr/node, 2 nodes/block. Phase 1: 16 edges x 8 heads threads stage
// exp(a), src, r into LDS (coalesced a_ws read, parallel exp). Phase 2: per-edge
// work is 1 broadcast LDS read + 1 independent v-load + fma (unroll-4 MLP).
// Bucket flush on run-change (wave-uniform, += into zeroed wsum).

__global__ __launch_bounds__(256) void k_aggregate8(
    const float* __restrict__ vbuf, const float* __restrict__ a_ws,
    const int* __restrict__ beg6, const int* __restrict__ esrc_s,
    const float* __restrict__ rel_msg,
    float* __restrict__ hacc, int n, int nE) {
    __shared__ float wsum[2][R_TYPES * 128];   // 6 KB
    __shared__ float exl[2][MAXB][H_HEADS];    // 1 KB
    __shared__ int   sl[2][MAXB];
    __shared__ int   rl[2][MAXB];
    __shared__ int   bb[2][2 * R_TYPES];       // beg[r], end[r]
    __shared__ int   cum[2][R_TYPES + 1];      // cumulative run lengths
    __shared__ int   dgmax_s;
    int tid = threadIdx.x;
    int nb = tid >> 7;
    int lane2 = tid & 127;
    int node = blockIdx.x * 2 + nb;
    bool valid = node < n;
    int h = lane2 >> 4;
    int d = lane2 & 15;
    if (lane2 < 2 * R_TYPES) {
        int rr = lane2 >= R_TYPES ? lane2 - R_TYPES : lane2;
        int key = rr * N_NODES + (valid ? node : 0);
        int val;
        if (lane2 < R_TYPES) val = valid ? beg6[key] : 0;
        else                 val = valid ? ((key + 1 < NKEYS) ? beg6[key + 1] : nE) : 0;
        bb[nb][lane2] = val;
    }
    if (tid == 0) dgmax_s = 0;
    __syncthreads();
    if (lane2 == 0) {
        int c = 0;
#pragma unroll
        for (int rr = 0; rr < R_TYPES; ++rr) {
            cum[nb][rr] = c;
            c += bb[nb][R_TYPES + rr] - bb[nb][rr];
        }
        cum[nb][R_TYPES] = c;
        atomicMax(&dgmax_s, c);
    }
    __syncthreads();
    int dg = cum[nb][R_TYPES];
    int dgmax = dgmax_s;

    float* wsn = &wsum[nb][0];
#pragma unroll
    for (int rr = 0; rr < R_TYPES; ++rr) wsn[rr * 128 + lane2] = 0.f;

    float den = 0.f;
    float racc = 0.f;
    int rcur = -1;
    int js = lane2 >> 3;        // staging edge slot 0..15
    int hs = lane2 & 7;         // staging head

    for (int base = 0; base < dgmax; base += MAXB) {
        __syncthreads();        // previous batch's readers done
        // ---- phase 1: stage up to 16 edges (exp in parallel) ----
        int jj = base + js;
        if (jj < dg) {
            int rr = 0;
#pragma unroll
            for (int q = 1; q < R_TYPES; ++q) if (jj >= cum[nb][q]) rr = q;
            int p = bb[nb][rr] + (jj - cum[nb][rr]);
            exl[nb][js][hs] = __expf(a_ws[(size_t)p * 8 + hs] - SM_SHIFT);
            if (hs == 0) { sl[nb][js] = esrc_s[p]; rl[nb][js] = rr; }
        }
        __syncthreads();
        // ---- phase 2: accumulate (independent v-loads, unroll for MLP) ----
        int cnt = dg - base; if (cnt > MAXB) cnt = MAXB; if (cnt < 0) cnt = 0;
#pragma unroll 4
        for (int j = 0; j < cnt; ++j) {
            int r = rl[nb][j];                     // wave-uniform broadcast
            if (r != rcur) {
                if (rcur >= 0) wsn[rcur * 128 + lane2] += racc;
                racc = 0.f;
                rcur = r;
            }
            float ex = exl[nb][j][h];
            den += ex;
            racc = fmaf(ex, vbuf[(size_t)sl[nb][j] * DIM + lane2], racc);
        }
    }
    if (rcur >= 0) wsn[rcur * 128 + lane2] += racc;
    __syncthreads();

    // epilogue: out[h][d] = (1/den) * sum_r sum_dp bucket[r][h][dp] * M[h][r][dp][d]
    float acc = 0.f;
#pragma unroll
    for (int rr = 0; rr < R_TYPES; ++rr) {
        const float*  M   = rel_msg + ((size_t)h * R_TYPES + rr) * 256;
        const float4* blr = (const float4*)&wsn[rr * 128 + h * 16];
#pragma unroll
        for (int dq = 0; dq < 4; ++dq) {
            float4 bv = blr[dq];
            acc = fmaf(bv.x, M[(dq * 4 + 0) * 16 + d], acc);
            acc = fmaf(bv.y, M[(dq * 4 + 1) * 16 + d], acc);
            acc = fmaf(bv.z, M[(dq * 4 + 2) * 16 + d], acc);
            acc = fmaf(bv.w, M[(dq * 4 + 3) * 16 + d], acc);
        }
    }
    if (valid)
        hacc[(size_t)node * DIM + lane2] = acc / fmaxf(den, 1e-9f);
}

// ======================= K4: tiled Wa + gate + residual + LayerNorm ===========

__global__ __launch_bounds__(256) void k_final_gemm(
    const float* __restrict__ x, const int* __restrict__ nlist,
    const int* __restrict__ tile_type, const int* __restrict__ ntiles_g,
    const float* __restrict__ Wa, const float* __restrict__ skip,
    const float* __restrict__ gamma, const float* __restrict__ beta,
    float* __restrict__ out) {
    __shared__ float hs[BN][DIM];
    __shared__ float ys[BN][DIM];
    __shared__ int sids[BN];
    __shared__ float mred[BN], ired[BN];
    int b = blockIdx.x;
    if (b >= *ntiles_g) return;
    int tid = threadIdx.x;
    if (tid < BN) sids[tid] = nlist[b * BN + tid];
    __syncthreads();
    for (int idx = tid; idx < BN * DIM; idx += 256) {
        int row = idx >> 7, col = idx & 127;
        int nid = sids[row];
        hs[row][col] = (nid >= 0) ? out[(size_t)nid * DIM + col] : 0.f;
    }
    __syncthreads();
    int t = tile_type[b];
    int half = tid >> 7, col = tid & 127;
    const float* W = Wa + (size_t)t * DIM * DIM;
    float acc[8];
#pragma unroll
    for (int n = 0; n < 8; ++n) acc[n] = 0.f;
#pragma unroll 4
    for (int d = 0; d < DIM; ++d) {
        float w = W[d * DIM + col];
#pragma unroll
        for (int n = 0; n < 8; ++n) acc[n] = fmaf(hs[half * 8 + n][d], w, acc[n]);
    }
    float gte = 1.f / (1.f + __expf(-skip[t]));
#pragma unroll
    for (int n = 0; n < 8; ++n) {
        int row = half * 8 + n;
        int nid = sids[row];
        float xv = (nid >= 0) ? x[(size_t)nid * DIM + col] : 0.f;
        ys[row][col] = xv * (2.f - gte) + acc[n] * gte;
    }
    __syncthreads();
    int ng = tid >> 4, l16 = tid & 15;
    float s = 0.f, s2 = 0.f;
#pragma unroll
    for (int k2 = 0; k2 < 8; ++k2) {
        float yv = ys[ng][l16 + 16 * k2];
        s += yv; s2 += yv * yv;
    }
#pragma unroll
    for (int m = 1; m < 16; m <<= 1) {
        s  += __shfl_xor(s, m, 64);
        s2 += __shfl_xor(s2, m, 64);
    }
    if (l16 == 0) {
        float mu = s * (1.f / DIM);
        float var = s2 * (1.f / DIM) - mu * mu;
        mred[ng] = mu;
        ired[ng] = rsqrtf(var + 1e-5f);
    }
    __syncthreads();
    float gm = gamma[col], bt = beta[col];
#pragma unroll
    for (int n = 0; n < 8; ++n) {
        int row = half * 8 + n;
        int nid = sids[row];
        if (nid >= 0)
            out[(size_t)nid * DIM + col] = (ys[row][col] - mred[row]) * ired[row] * gm + bt;
    }
}

// ======================= launcher =======================

extern "C" void kernel_launch(void* const* d_in, const int* in_sizes, int n_in,
                              void* d_out, int out_size, void* d_ws, size_t ws_size,
                              hipStream_t stream) {
    const float* x       = (const float*)d_in[0];
    const int*   src     = (const int*)d_in[1];
    const int*   dst     = (const int*)d_in[2];
    const int*   ntype   = (const int*)d_in[3];
    const int*   etype   = (const int*)d_in[4];
    const float* Wk      = (const float*)d_in[5];
    const float* Wq      = (const float*)d_in[6];
    const float* Wv      = (const float*)d_in[7];
    const float* Wa      = (const float*)d_in[8];
    const float* rel_pri = (const float*)d_in[9];
    const float* rel_att = (const float*)d_in[10];
    const float* rel_msg = (const float*)d_in[11];
    const float* skip    = (const float*)d_in[12];
    const float* gamma   = (const float*)d_in[13];
    const float* beta    = (const float*)d_in[14];
    float* out = (float*)d_out;

    const int N = N_NODES, E = N_EDGES;

    // workspace layout
    char* ws = (char*)d_ws;
    float* kb   = (float*)ws;                          // N*128
    float* qb   = kb + (size_t)N * DIM;                // N*128
    float* vb   = qb + (size_t)N * DIM;                // N*128
    float* a_ws = vb + (size_t)N * DIM;                // E*8
    int* deg6    = (int*)(a_ws + (size_t)E * H_HEADS); // NKEYS
    int* beg6    = deg6 + NKEYS;                       // NKEYS
    int* cursor6 = beg6 + NKEYS;                       // NKEYS
    int* partial6 = cursor6 + NKEYS;                   // NBLK_K
    int* esrc_s  = partial6 + NBLK_K;                  // E
    int* edst_s  = esrc_s + E;                         // E
    int* tcnt    = edst_s + E;                         // 4
    int* pbase   = tcnt + T_TYPES;                     // 4
    int* ntiles  = pbase + T_TYPES;                    // 1
    int* tile_type = ntiles + 1;                       // MAX_TILES
    int* nlist   = tile_type + MAX_TILES;              // MAX_TILES*BN
    int* wpos    = nlist + (size_t)MAX_TILES * BN;     // N

    const int nbScan = (N + 255) / 256;

    // r-major (r,dst)-keyed CSR build (single sort serves edge_a AND aggregate)
    hipMemsetAsync(deg6, 0, (size_t)NKEYS * sizeof(int), stream);
    k_count6<<<(E + 255) / 256, 256, 0, stream>>>(dst, etype, deg6, E);
    k_scanA<<<NBLK_K, 256, 0, stream>>>(deg6, beg6, partial6, NKEYS);
    k_rscan<<<1, 256, 0, stream>>>(partial6, NBLK_K);
    k_scanC2<<<NBLK_K, 256, 0, stream>>>(beg6, partial6, cursor6, NKEYS);
    k_scatter6<<<(E + 255) / 256, 256, 0, stream>>>(
        src, dst, etype, cursor6, esrc_s, edst_s, E);

    // node type buckets (padded 16-node tiles)
    hipMemsetAsync(tcnt, 0, T_TYPES * sizeof(int), stream);
    k_tcount_agg<<<nbScan, 256, 0, stream>>>(ntype, tcnt, wpos, N);
    k_tsetup<<<1, 256, 0, stream>>>(tcnt, pbase, ntiles, tile_type);
    hipMemsetAsync(nlist, 0xFF, (size_t)MAX_TILES * BN * sizeof(int), stream);
    k_tscatter2<<<nbScan, 256, 0, stream>>>(ntype, wpos, pbase, nlist, N);

    // projections (tiled per-type GEMM, full-chip grid)
    k_kqv_gemm3<<<MAX_TILES, 192, 0, stream>>>(
        x, nlist, tile_type, ntiles, Wk, Wq, Wv, kb, qb, vb);

    // edge logits (r-sorted by construction, coalesced a_ws write)
    k_edge_a3<<<(E + 31) / 32, 256, 0, stream>>>(
        kb, qb, esrc_s, edst_s, beg6, rel_att, rel_pri, a_ws, E);

    // per-node softmax + message aggregation -> d_out (scratch)
    k_aggregate8<<<(N + 1) / 2, 256, 0, stream>>>(
        vb, a_ws, beg6, esrc_s, rel_msg, out, N, E);

    // output projection + gate + residual + LayerNorm (in place on d_out)
    k_final_gemm<<<MAX_TILES, 256, 0, stream>>>(
        x, nlist, tile_type, ntiles, Wa, skip, gamma, beta, out);
}